// Round 1
// baseline (2557.149 us; speedup 1.0000x reference)
//
#include <hip/hip_runtime.h>

typedef unsigned short u16;
typedef unsigned int u32;
typedef __attribute__((ext_vector_type(8))) short short8v;   // 8 bf16 (4 VGPRs)
typedef __attribute__((ext_vector_type(4))) float f32x4;

#define MFMA16(a,b,c) __builtin_amdgcn_mfma_f32_16x16x32_bf16((a),(b),(c),0,0,0)

__device__ __forceinline__ u16 f2bf(float f){
  u32 u = __float_as_uint(f);
  return (u16)((u + 0x7fffu + ((u >> 16) & 1u)) >> 16);   // RNE
}
__device__ __forceinline__ float bf2f(u16 h){ return __uint_as_float(((u32)h) << 16); }
__device__ __forceinline__ float gelu_f(float x){ return 0.5f * x * (1.f + erff(x * 0.70710678118654752f)); }
__device__ __forceinline__ float sigm_f(float x){ return 1.f / (1.f + __expf(-x)); }

__device__ __forceinline__ short8v load_a8(const float* __restrict__ p){
  float4 v0 = *(const float4*)(p);
  float4 v1 = *(const float4*)(p + 4);
  short8v r;
  r[0]=(short)f2bf(v0.x); r[1]=(short)f2bf(v0.y); r[2]=(short)f2bf(v0.z); r[3]=(short)f2bf(v0.w);
  r[4]=(short)f2bf(v1.x); r[5]=(short)f2bf(v1.y); r[6]=(short)f2bf(v1.z); r[7]=(short)f2bf(v1.w);
  return r;
}

// ---------------- weight cast fp32 -> bf16 ----------------
__global__ __launch_bounds__(256) void cast_k(const float* __restrict__ s, u16* __restrict__ d, int n){
  int i = (blockIdx.x * 256 + threadIdx.x) * 4;
  if (i + 3 < n){
    float4 v = *(const float4*)(s + i);
    ushort4 o; o.x = f2bf(v.x); o.y = f2bf(v.y); o.z = f2bf(v.z); o.w = f2bf(v.w);
    *(ushort4*)(d + i) = o;
  }
}

// ---------------- init: ps = comp[:,0,:]; zero LSTM state; proof_steps[0] ----------------
__global__ __launch_bounds__(256) void init_k(const float* __restrict__ comp, float* ps0, float* outp,
                                              float* h0, float* c0, float* h1, float* c1){
  int i = blockIdx.x * 256 + threadIdx.x;       // 32768
  int b = i >> 10, hh = i & 1023;
  float v = comp[(size_t)b * 1048576 + hh];
  ps0[i] = v; outp[i] = v;
  h0[i] = 0.f; c0[i] = 0.f; h1[i] = 0.f; c1[i] = 0.f;
}

// ---------------- K/V precompute GEMM: C = A @ W^T + b (bf16 out), 128x128 tile ----------------
__global__ __launch_bounds__(256) void gemmkv_k(const float* __restrict__ A,
    const u16* __restrict__ Wk, const u16* __restrict__ Wv,
    const float* __restrict__ bk, const float* __restrict__ bv,
    u16* __restrict__ Kb, u16* __restrict__ Vb)
{
  const u16* W; const float* bias; u16* C;
  if (blockIdx.z == 0){ W = Wk; bias = bk; C = Kb; } else { W = Wv; bias = bv; C = Vb; }
  int m0 = blockIdx.x * 128, n0 = blockIdx.y * 128;
  __shared__ u16 As[128 * 32];
  __shared__ u16 Bs[128 * 32];
  int tid = threadIdx.x;
  int w = tid >> 6, l = tid & 63, lr = l & 15, lk = l >> 4;
  int wm = (w >> 1) * 64, wn = (w & 1) * 64;
  f32x4 acc[4][4];
  #pragma unroll
  for (int i = 0; i < 4; i++)
    #pragma unroll
    for (int j = 0; j < 4; j++) acc[i][j] = (f32x4){0.f,0.f,0.f,0.f};

  for (int kc = 0; kc < 1024; kc += 32){
    __syncthreads();
    #pragma unroll
    for (int u = 0; u < 4; u++){            // stage A (fp32 -> bf16): 128 rows x 32 k
      int i = tid + u * 256;
      int row = i >> 3, kq = (i & 7) * 4;
      float4 v = *(const float4*)(A + (size_t)(m0 + row) * 1024 + kc + kq);
      uint2 pk;
      pk.x = (u32)f2bf(v.x) | ((u32)f2bf(v.y) << 16);
      pk.y = (u32)f2bf(v.z) | ((u32)f2bf(v.w) << 16);
      *(uint2*)(As + row * 32 + kq) = pk;
    }
    #pragma unroll
    for (int u = 0; u < 2; u++){            // stage B (bf16): 128 rows x 32 k
      int i = tid + u * 256;
      int row = i >> 2, kq = (i & 3) * 8;
      *(uint4*)(Bs + row * 32 + kq) = *(const uint4*)(W + (size_t)(n0 + row) * 1024 + kc + kq);
    }
    __syncthreads();
    short8v a[4], bb[4];
    #pragma unroll
    for (int mi = 0; mi < 4; mi++) a[mi]  = *(const short8v*)(As + (wm + mi * 16 + lr) * 32 + lk * 8);
    #pragma unroll
    for (int ni = 0; ni < 4; ni++) bb[ni] = *(const short8v*)(Bs + (wn + ni * 16 + lr) * 32 + lk * 8);
    #pragma unroll
    for (int mi = 0; mi < 4; mi++)
      #pragma unroll
      for (int ni = 0; ni < 4; ni++)
        acc[mi][ni] = MFMA16(a[mi], bb[ni], acc[mi][ni]);
  }
  #pragma unroll
  for (int mi = 0; mi < 4; mi++)
    #pragma unroll
    for (int ni = 0; ni < 4; ni++)
      #pragma unroll
      for (int r = 0; r < 4; r++){
        int row = m0 + wm + mi * 16 + lk * 4 + r;
        int col = n0 + wn + ni * 16 + lr;
        C[(size_t)row * 1024 + col] = f2bf(acc[mi][ni][r] + bias[col]);
      }
}

// ---------------- generic M=32 linear: out = act(X1@W1^T [+ X2@W2^T] + b1 [+ b2]) ----------------
// 8 waves split K; each wave does 32x32 output via 2x2 16x16x32 MFMA frags; LDS cross-wave reduce.
__global__ __launch_bounds__(512) void lin_k(
    const float* __restrict__ X1, int K1, const u16* __restrict__ W1, int ld1, const float* __restrict__ b1,
    const float* __restrict__ X2, int K2, const u16* __restrict__ W2, int ld2, const float* __restrict__ b2,
    float* __restrict__ out, int N, int act, float scale, float* __restrict__ out2)
{
  int c0 = blockIdx.x * 32;
  int tid = threadIdx.x, w = tid >> 6, l = tid & 63, lr = l & 15, lk = l >> 4;
  f32x4 acc[2][2];
  #pragma unroll
  for (int i = 0; i < 2; i++)
    #pragma unroll
    for (int j = 0; j < 2; j++) acc[i][j] = (f32x4){0.f,0.f,0.f,0.f};

  {
    int chunk = K1 >> 3;
    int kb0 = w * chunk + lk * 8;
    for (int kk = 0; kk < chunk; kk += 32){
      int kb = kb0 + kk;
      short8v a0 = load_a8(X1 + (size_t)lr * K1 + kb);
      short8v a1 = load_a8(X1 + (size_t)(lr + 16) * K1 + kb);
      short8v w0 = *(const short8v*)(W1 + (size_t)(c0 + lr) * ld1 + kb);
      short8v w1 = *(const short8v*)(W1 + (size_t)(c0 + lr + 16) * ld1 + kb);
      acc[0][0] = MFMA16(a0, w0, acc[0][0]);
      acc[0][1] = MFMA16(a0, w1, acc[0][1]);
      acc[1][0] = MFMA16(a1, w0, acc[1][0]);
      acc[1][1] = MFMA16(a1, w1, acc[1][1]);
    }
  }
  if (X2){
    int chunk = K2 >> 3;
    int kb0 = w * chunk + lk * 8;
    for (int kk = 0; kk < chunk; kk += 32){
      int kb = kb0 + kk;
      short8v a0 = load_a8(X2 + (size_t)lr * K2 + kb);
      short8v a1 = load_a8(X2 + (size_t)(lr + 16) * K2 + kb);
      short8v w0 = *(const short8v*)(W2 + (size_t)(c0 + lr) * ld2 + kb);
      short8v w1 = *(const short8v*)(W2 + (size_t)(c0 + lr + 16) * ld2 + kb);
      acc[0][0] = MFMA16(a0, w0, acc[0][0]);
      acc[0][1] = MFMA16(a0, w1, acc[0][1]);
      acc[1][0] = MFMA16(a1, w0, acc[1][0]);
      acc[1][1] = MFMA16(a1, w1, acc[1][1]);
    }
  }
  __shared__ float red[8][32][32];
  #pragma unroll
  for (int mi = 0; mi < 2; mi++)
    #pragma unroll
    for (int ni = 0; ni < 2; ni++)
      #pragma unroll
      for (int r = 0; r < 4; r++)
        red[w][mi * 16 + lk * 4 + r][ni * 16 + lr] = acc[mi][ni][r];
  __syncthreads();
  for (int i = tid; i < 1024; i += 512){
    int row = i >> 5, col = i & 31;
    float v = 0.f;
    #pragma unroll
    for (int ww = 0; ww < 8; ww++) v += red[ww][row][col];
    v += b1[c0 + col];
    if (b2) v += b2[c0 + col];
    if (act == 1) v = gelu_f(v);
    else if (act == 2) v *= scale;
    out[(size_t)row * N + c0 + col] = v;
    if (out2) out2[(size_t)row * N + c0 + col] = v;
  }
}

// ---------------- rule head: logits -> softmax -> probs out + sel = probs @ rule_emb ----------------
__global__ __launch_bounds__(256) void rule2_k(const float* __restrict__ h1, const float* __restrict__ w2,
    const float* __restrict__ b2, const float* __restrict__ emb,
    float* __restrict__ probs_out, float* __restrict__ sel)
{
  int b = blockIdx.x, tid = threadIdx.x;
  __shared__ float lg[32], pshared[32];
  int j = tid >> 3, l8 = tid & 7;
  const float* xr = h1 + b * 1024;
  const float* wr = w2 + j * 1024;
  float acc = 0.f;
  #pragma unroll 8
  for (int kk = 0; kk < 32; kk++){
    int k = kk * 32 + l8 * 4;
    float4 xv = *(const float4*)(xr + k);
    float4 wv = *(const float4*)(wr + k);
    acc += xv.x * wv.x + xv.y * wv.y + xv.z * wv.z + xv.w * wv.w;
  }
  acc += __shfl_xor(acc, 1); acc += __shfl_xor(acc, 2); acc += __shfl_xor(acc, 4);
  if (l8 == 0) lg[j] = acc + b2[j];
  __syncthreads();
  if (tid < 32){
    float v = lg[tid];
    float m = v;
    for (int o = 1; o < 32; o <<= 1) m = fmaxf(m, __shfl_xor(m, o));
    float e = __expf(v - m);
    float s = e;
    for (int o = 1; o < 32; o <<= 1) s += __shfl_xor(s, o);
    float p = e / s;
    pshared[tid] = p;
    probs_out[b * 32 + tid] = p;
  }
  __syncthreads();
  for (int j2 = tid; j2 < 1024; j2 += 256){
    float a2 = 0.f;
    #pragma unroll
    for (int r = 0; r < 32; r++) a2 += pshared[r] * emb[r * 1024 + j2];
    sel[b * 1024 + j2] = a2;
  }
}

// ---------------- attention: scores -> softmax -> (a to ws) -> ctx0, one block per (b,h) ----------------
__global__ __launch_bounds__(256) void attn_k(const float* __restrict__ q,
    const u16* __restrict__ Kb, const u16* __restrict__ Vb,
    float* __restrict__ afull, float* __restrict__ ctx0)
{
  int bh = blockIdx.x;                 // b*16 + h
  int b = bh >> 4, h = bh & 15;
  int tid = threadIdx.x;
  __shared__ float qs[64];
  __shared__ float sc[1024];
  __shared__ float rmx[4], rsm[4];
  __shared__ float ctxp[8][64];
  if (tid < 64) qs[tid] = q[bh * 64 + tid];
  __syncthreads();
  float myS[4];
  #pragma unroll
  for (int i = 0; i < 4; i++){
    int s = tid + i * 256;
    const u16* kr = Kb + ((size_t)(b * 1024 + s) * 16 + h) * 64;
    float acc = 0.f;
    #pragma unroll
    for (int c = 0; c < 8; c++){
      uint4 kv = *(const uint4*)(kr + c * 8);
      float4 q0 = *(const float4*)(qs + c * 8);
      float4 q1 = *(const float4*)(qs + c * 8 + 4);
      acc += q0.x * bf2f((u16)(kv.x & 0xffff)) + q0.y * bf2f((u16)(kv.x >> 16))
           + q0.z * bf2f((u16)(kv.y & 0xffff)) + q0.w * bf2f((u16)(kv.y >> 16))
           + q1.x * bf2f((u16)(kv.z & 0xffff)) + q1.y * bf2f((u16)(kv.z >> 16))
           + q1.z * bf2f((u16)(kv.w & 0xffff)) + q1.w * bf2f((u16)(kv.w >> 16));
    }
    myS[i] = acc;
  }
  float mx = fmaxf(fmaxf(myS[0], myS[1]), fmaxf(myS[2], myS[3]));
  for (int o = 1; o < 64; o <<= 1) mx = fmaxf(mx, __shfl_xor(mx, o));
  if ((tid & 63) == 0) rmx[tid >> 6] = mx;
  __syncthreads();
  mx = fmaxf(fmaxf(rmx[0], rmx[1]), fmaxf(rmx[2], rmx[3]));
  float e[4], sm = 0.f;
  #pragma unroll
  for (int i = 0; i < 4; i++){ e[i] = __expf(myS[i] - mx); sm += e[i]; }
  for (int o = 1; o < 64; o <<= 1) sm += __shfl_xor(sm, o);
  if ((tid & 63) == 0) rsm[tid >> 6] = sm;
  __syncthreads();
  sm = rsm[0] + rsm[1] + rsm[2] + rsm[3];
  float inv = 1.f / sm;
  float* ar = afull + (size_t)bh * 1024;
  #pragma unroll
  for (int i = 0; i < 4; i++){
    int s = tid + i * 256;
    float a = e[i] * inv;
    sc[s] = a;
    ar[s] = a;
  }
  __syncthreads();
  int d2 = (tid & 31) * 2, chunk = tid >> 5;        // 8 chunks of 128 s
  const u16* vb = Vb + ((size_t)(b * 1024) * 16 + h) * 64 + d2;
  float a0 = 0.f, a1 = 0.f;
  for (int s = chunk * 128; s < chunk * 128 + 128; s++){
    u32 vv = *(const u32*)(vb + (size_t)s * 1024);
    float wv = sc[s];
    a0 += wv * bf2f((u16)(vv & 0xffff));
    a1 += wv * bf2f((u16)(vv >> 16));
  }
  *(float2*)&ctxp[chunk][d2] = make_float2(a0, a1);
  __syncthreads();
  if (tid < 64){
    float r = 0.f;
    #pragma unroll
    for (int c = 0; c < 8; c++) r += ctxp[c][tid];
    ctx0[bh * 64 + tid] = r;
  }
}

// ---------------- attn mean over heads ----------------
__global__ __launch_bounds__(256) void attnavg_k(const float* __restrict__ afull, float* __restrict__ out){
  int idx = blockIdx.x * 256 + threadIdx.x;     // 32768
  int b = idx >> 10, s = idx & 1023;
  float acc = 0.f;
  #pragma unroll
  for (int h = 0; h < 16; h++) acc += afull[((size_t)(b * 16 + h)) * 1024 + s];
  out[idx] = acc * (1.f / 16.f);
}

// ---------------- LSTM gates ----------------
__global__ __launch_bounds__(256) void gates_k(const float* __restrict__ g, const float* __restrict__ cprev,
                                               float* __restrict__ cn, float* __restrict__ hn){
  int idx = blockIdx.x * 256 + threadIdx.x;     // 32768
  int b = idx >> 10, j = idx & 1023;
  const float* gr = g + (size_t)b * 4096;
  float gi = gr[j], gf = gr[1024 + j], gg = gr[2048 + j], go = gr[3072 + j];
  float c = sigm_f(gf) * cprev[idx] + sigm_f(gi) * tanhf(gg);
  cn[idx] = c;
  hn[idx] = sigm_f(go) * tanhf(c);
}

// ---------------- si = ps + sel + ctx + mem_out ----------------
__global__ __launch_bounds__(256) void sum4_k(const float* __restrict__ a, const float* __restrict__ b,
                                              const float* __restrict__ c, const float* __restrict__ d,
                                              float* __restrict__ o){
  int i = blockIdx.x * 256 + threadIdx.x;
  o[i] = a[i] + b[i] + c[i] + d[i];
}

// ---------------- layernorm(2048) + gelu, one block per row ----------------
__global__ __launch_bounds__(256) void lngelu_k(const float* __restrict__ z, const float* __restrict__ g,
                                                const float* __restrict__ bta, float* __restrict__ zg){
  int bb = blockIdx.x, tid = threadIdx.x;
  const float* zr = z + (size_t)bb * 2048;
  float v[8]; float s = 0.f;
  #pragma unroll
  for (int i = 0; i < 8; i++){ v[i] = zr[tid + i * 256]; s += v[i]; }
  __shared__ float red[4], red2[4];
  for (int o = 1; o < 64; o <<= 1) s += __shfl_xor(s, o);
  if ((tid & 63) == 0) red[tid >> 6] = s;
  __syncthreads();
  float mu = (red[0] + red[1] + red[2] + red[3]) * (1.f / 2048.f);
  float s2 = 0.f;
  #pragma unroll
  for (int i = 0; i < 8; i++){ float d = v[i] - mu; s2 += d * d; }
  for (int o = 1; o < 64; o <<= 1) s2 += __shfl_xor(s2, o);
  if ((tid & 63) == 0) red2[tid >> 6] = s2;
  __syncthreads();
  float var = (red2[0] + red2[1] + red2[2] + red2[3]) * (1.f / 2048.f);
  float rstd = rsqrtf(var + 1e-5f);
  float* zo = zg + (size_t)bb * 2048;
  #pragma unroll
  for (int i = 0; i < 8; i++){
    int idx = tid + i * 256;
    float y = (v[i] - mu) * rstd * g[idx] + bta[idx];
    zo[idx] = gelu_f(y);
  }
}

// ---------------- 32 rows dot w (K=1024) -> sigmoid ----------------
__global__ __launch_bounds__(256) void dotsig_k(const float* __restrict__ x, const float* __restrict__ w,
                                                const float* __restrict__ bias, float* __restrict__ out){
  int b = threadIdx.x >> 3, l8 = threadIdx.x & 7;
  const float* xr = x + (size_t)b * 1024;
  float acc = 0.f;
  #pragma unroll 8
  for (int kk = 0; kk < 32; kk++){
    int k = kk * 32 + l8 * 4;
    float4 xv = *(const float4*)(xr + k);
    float4 wv = *(const float4*)(w + k);
    acc += xv.x * wv.x + xv.y * wv.y + xv.z * wv.z + xv.w * wv.w;
  }
  acc += __shfl_xor(acc, 1); acc += __shfl_xor(acc, 2); acc += __shfl_xor(acc, 4);
  if (l8 == 0) out[b] = sigm_f(acc + bias[0]);
}

extern "C" void kernel_launch(void* const* d_in, const int* in_sizes, int n_in,
                              void* d_out, int out_size, void* d_ws, size_t ws_size,
                              hipStream_t stream) {
  const float* comp      = (const float*)d_in[0];
  const float* rule_w1   = (const float*)d_in[2];
  const float* rule_b1   = (const float*)d_in[3];
  const float* rule_w2   = (const float*)d_in[4];
  const float* rule_b2   = (const float*)d_in[5];
  const float* rule_emb  = (const float*)d_in[6];
  const float* attn_in_w = (const float*)d_in[7];
  const float* attn_in_b = (const float*)d_in[8];
  const float* attn_out_w= (const float*)d_in[9];
  const float* attn_out_b= (const float*)d_in[10];
  const float* wih0 = (const float*)d_in[11];
  const float* whh0 = (const float*)d_in[12];
  const float* bih0 = (const float*)d_in[13];
  const float* bhh0 = (const float*)d_in[14];
  const float* wih1 = (const float*)d_in[15];
  const float* whh1 = (const float*)d_in[16];
  const float* bih1 = (const float*)d_in[17];
  const float* bhh1 = (const float*)d_in[18];
  const float* gen_w1 = (const float*)d_in[19];
  const float* gen_b1 = (const float*)d_in[20];
  const float* ln_g   = (const float*)d_in[21];
  const float* ln_b   = (const float*)d_in[22];
  const float* gen_w2 = (const float*)d_in[23];
  const float* gen_b2 = (const float*)d_in[24];
  const float* val_w1 = (const float*)d_in[25];
  const float* val_b1 = (const float*)d_in[26];
  const float* val_w2 = (const float*)d_in[27];
  const float* val_b2 = (const float*)d_in[28];
  const float* ver_w1 = (const float*)d_in[29];
  const float* ver_b1 = (const float*)d_in[30];
  const float* ver_w2 = (const float*)d_in[31];
  const float* ver_b2 = (const float*)d_in[32];

  float* out_f     = (float*)d_out;
  float* out_proof = out_f;                       // (17,32,1024)
  float* out_valid = out_f + 17 * 32768;          // (32,1)
  float* out_probs = out_valid + 32;              // (16,32,32)
  float* out_vals  = out_probs + 16 * 1024;       // (16,32,1)
  float* out_attn  = out_vals + 16 * 32;          // (16,32,1024)

  char* wp = (char*)d_ws;
  auto carve = [&](size_t bytes) -> void* {
    void* p = (void*)wp; wp += (bytes + 255) & ~(size_t)255; return p;
  };
  u16* Kb    = (u16*)carve((size_t)33554432 * 2);
  u16* Vb    = (u16*)carve((size_t)33554432 * 2);
  u16* rw1b  = (u16*)carve(2097152);
  u16* wqb   = (u16*)carve(2097152);
  u16* wkb   = (u16*)carve(2097152);
  u16* wvb   = (u16*)carve(2097152);
  u16* aowb  = (u16*)carve(2097152);
  u16* wih0b = (u16*)carve(8388608);
  u16* whh0b = (u16*)carve(8388608);
  u16* wih1b = (u16*)carve(8388608);
  u16* whh1b = (u16*)carve(8388608);
  u16* gw1b  = (u16*)carve(4194304);
  u16* gw2b  = (u16*)carve(4194304);
  u16* vw1b  = (u16*)carve(4194304);
  u16* verw1b= (u16*)carve(2097152);
  float* psb[2]  = { (float*)carve(131072), (float*)carve(131072) };
  float* h0b[2]  = { (float*)carve(131072), (float*)carve(131072) };
  float* c0b[2]  = { (float*)carve(131072), (float*)carve(131072) };
  float* h1b[2]  = { (float*)carve(131072), (float*)carve(131072) };
  float* c1b[2]  = { (float*)carve(131072), (float*)carve(131072) };
  float* h1act = (float*)carve(131072);
  float* sel   = (float*)carve(131072);
  float* qbuf  = (float*)carve(131072);
  float* ctx0  = (float*)carve(131072);
  float* ctxb  = (float*)carve(131072);
  float* sibuf = (float*)carve(131072);
  float* v1buf = (float*)carve(131072);
  float* gbuf  = (float*)carve(524288);
  float* zbuf  = (float*)carve(262144);
  float* zgbuf = (float*)carve(262144);
  float* afull = (float*)carve(2097152);
  (void)ws_size; (void)in_sizes; (void)n_in; (void)out_size;

  auto cast = [&](const float* s, u16* d, int n){
    cast_k<<<dim3((n / 4 + 255) / 256), dim3(256), 0, stream>>>(s, d, n);
  };
  cast(rule_w1, rw1b, 1048576);
  cast(attn_in_w,            wqb, 1048576);
  cast(attn_in_w + 1048576,  wkb, 1048576);
  cast(attn_in_w + 2097152,  wvb, 1048576);
  cast(attn_out_w, aowb, 1048576);
  cast(wih0, wih0b, 4194304);
  cast(whh0, whh0b, 4194304);
  cast(wih1, wih1b, 4194304);
  cast(whh1, whh1b, 4194304);
  cast(gen_w1, gw1b, 2097152);
  cast(gen_w2, gw2b, 2097152);
  cast(val_w1, vw1b, 2097152);
  cast(ver_w1, verw1b, 1048576);

  gemmkv_k<<<dim3(256, 8, 2), dim3(256), 0, stream>>>(comp, wkb, wvb,
      attn_in_b + 1024, attn_in_b + 2048, Kb, Vb);

  init_k<<<dim3(128), dim3(256), 0, stream>>>(comp, psb[0], out_proof,
      h0b[0], c0b[0], h1b[0], c1b[0]);

  auto lin = [&](const float* X1, int K1, const u16* W1, int ld1, const float* bb1,
                 const float* X2, int K2, const u16* W2, int ld2, const float* bb2,
                 float* out, int N, int act, float scl, float* out2){
    lin_k<<<dim3(N / 32), dim3(512), 0, stream>>>(X1, K1, W1, ld1, bb1,
                                                  X2, K2, W2, ld2, bb2,
                                                  out, N, act, scl, out2);
  };

  for (int t = 0; t < 16; t++){
    int cur = t & 1, nx = cur ^ 1;
    // rule selection
    lin(psb[cur], 1024, rw1b, 1024, rule_b1, nullptr, 0, nullptr, 0, nullptr,
        h1act, 1024, 1, 0.f, nullptr);
    rule2_k<<<dim3(32), dim3(256), 0, stream>>>(h1act, rule_w2, rule_b2, rule_emb,
        out_probs + t * 1024, sel);
    // attention
    lin(psb[cur], 1024, wqb, 1024, attn_in_b, nullptr, 0, nullptr, 0, nullptr,
        qbuf, 1024, 2, 0.125f, nullptr);
    attn_k<<<dim3(512), dim3(256), 0, stream>>>(qbuf, Kb, Vb, afull, ctx0);
    attnavg_k<<<dim3(128), dim3(256), 0, stream>>>(afull, out_attn + (size_t)t * 32768);
    lin(ctx0, 1024, aowb, 1024, attn_out_b, nullptr, 0, nullptr, 0, nullptr,
        ctxb, 1024, 0, 0.f, nullptr);
    // LSTM x2
    lin(psb[cur], 1024, wih0b, 1024, bih0, h0b[cur], 1024, whh0b, 1024, bhh0,
        gbuf, 4096, 0, 0.f, nullptr);
    gates_k<<<dim3(128), dim3(256), 0, stream>>>(gbuf, c0b[cur], c0b[nx], h0b[nx]);
    lin(h0b[nx], 1024, wih1b, 1024, bih1, h1b[cur], 1024, whh1b, 1024, bhh1,
        gbuf, 4096, 0, 0.f, nullptr);
    gates_k<<<dim3(128), dim3(256), 0, stream>>>(gbuf, c1b[cur], c1b[nx], h1b[nx]);
    // generator
    sum4_k<<<dim3(128), dim3(256), 0, stream>>>(psb[cur], sel, ctxb, h1b[nx], sibuf);
    lin(sibuf, 1024, gw1b, 1024, gen_b1, nullptr, 0, nullptr, 0, nullptr,
        zbuf, 2048, 0, 0.f, nullptr);
    lngelu_k<<<dim3(32), dim3(256), 0, stream>>>(zbuf, ln_g, ln_b, zgbuf);
    lin(zgbuf, 2048, gw2b, 2048, gen_b2, nullptr, 0, nullptr, 0, nullptr,
        psb[nx], 1024, 0, 0.f, out_proof + (size_t)(t + 1) * 32768);
    // value head: cat[ps, nxt]
    lin(psb[cur], 1024, vw1b, 2048, val_b1, psb[nx], 1024, vw1b + 1024, 2048, nullptr,
        v1buf, 1024, 1, 0.f, nullptr);
    dotsig_k<<<dim3(1), dim3(256), 0, stream>>>(v1buf, val_w2, val_b2, out_vals + t * 32);
  }
  // verifier (final state is psb[0] after 16 steps)
  lin(psb[0], 1024, verw1b, 1024, ver_b1, nullptr, 0, nullptr, 0, nullptr,
      v1buf, 1024, 1, 0.f, nullptr);
  dotsig_k<<<dim3(1), dim3(256), 0, stream>>>(v1buf, ver_w2, ver_b2, out_valid);
}

// Round 2
// 2220.170 us; speedup vs baseline: 1.1518x; 1.1518x over previous
//
#include <hip/hip_runtime.h>

typedef unsigned short u16;
typedef unsigned int u32;
typedef __attribute__((ext_vector_type(8))) short short8v;   // 8 bf16 (4 VGPRs)
typedef __attribute__((ext_vector_type(4))) float f32x4;

#define MFMA16(a,b,c) __builtin_amdgcn_mfma_f32_16x16x32_bf16((a),(b),(c),0,0,0)

__device__ __forceinline__ u16 f2bf(float f){
  u32 u = __float_as_uint(f);
  return (u16)((u + 0x7fffu + ((u >> 16) & 1u)) >> 16);   // RNE
}
__device__ __forceinline__ float bf2f(u16 h){ return __uint_as_float(((u32)h) << 16); }
__device__ __forceinline__ float gelu_f(float x){ return 0.5f * x * (1.f + erff(x * 0.70710678118654752f)); }
__device__ __forceinline__ float sigm_f(float x){ return 1.f / (1.f + __expf(-x)); }
__device__ __forceinline__ void acc4(float4& a, const float4 b){ a.x+=b.x; a.y+=b.y; a.z+=b.z; a.w+=b.w; }

// ---------------- fused weight cast fp32 -> bf16 (13 jobs, one launch) ----------------
struct CastJobs { const float* s[13]; u16* d[13]; int start[14]; };
__global__ __launch_bounds__(256) void cast_all_k(CastJobs J){
  int bx = blockIdx.x, j = 0;
  #pragma unroll
  for (int t = 0; t < 13; t++) if (bx >= J.start[t + 1]) j = t + 1;
  int i = (bx - J.start[j]) * 1024 + threadIdx.x * 4;
  float4 v = *(const float4*)(J.s[j] + i);
  ushort4 o; o.x = f2bf(v.x); o.y = f2bf(v.y); o.z = f2bf(v.z); o.w = f2bf(v.w);
  *(ushort4*)(J.d[j] + i) = o;
}

// ---------------- init: ps = comp[:,0,:]; zero LSTM state; proof_steps[0] ----------------
__global__ __launch_bounds__(256) void init_k(const float* __restrict__ comp, float* ps0, float* outp,
                                              float* h0, float* c0, float* h1, float* c1){
  int i = blockIdx.x * 256 + threadIdx.x;       // 32768
  int b = i >> 10, hh = i & 1023;
  float v = comp[(size_t)b * 1048576 + hh];
  ps0[i] = v; outp[i] = v;
  h0[i] = 0.f; c0[i] = 0.f; h1[i] = 0.f; c1[i] = 0.f;
}

// ---------------- V GEMM: V[b][s][h][d] = comp @ Wv^T + bv (bf16) ----------------
__global__ __launch_bounds__(256) void gemmv_k(const float* __restrict__ A,
    const u16* __restrict__ W, const float* __restrict__ bias, u16* __restrict__ C)
{
  int m0 = blockIdx.x * 128, n0 = blockIdx.y * 128;   // m over (b,s), n over (h,d)
  __shared__ u16 As[128 * 32];
  __shared__ u16 Bs[128 * 32];
  int tid = threadIdx.x;
  int w = tid >> 6, l = tid & 63, lr = l & 15, lk = l >> 4;
  int wm = (w >> 1) * 64, wn = (w & 1) * 64;
  f32x4 acc[4][4];
  #pragma unroll
  for (int i = 0; i < 4; i++)
    #pragma unroll
    for (int j = 0; j < 4; j++) acc[i][j] = (f32x4){0.f,0.f,0.f,0.f};

  for (int kc = 0; kc < 1024; kc += 32){
    __syncthreads();
    #pragma unroll
    for (int u = 0; u < 4; u++){            // stage A (fp32 -> bf16)
      int i = tid + u * 256;
      int row = i >> 3, kq = (i & 7) * 4;
      float4 v = *(const float4*)(A + (size_t)(m0 + row) * 1024 + kc + kq);
      uint2 pk;
      pk.x = (u32)f2bf(v.x) | ((u32)f2bf(v.y) << 16);
      pk.y = (u32)f2bf(v.z) | ((u32)f2bf(v.w) << 16);
      *(uint2*)(As + row * 32 + kq) = pk;
    }
    #pragma unroll
    for (int u = 0; u < 2; u++){            // stage B (bf16)
      int i = tid + u * 256;
      int row = i >> 2, kq = (i & 3) * 8;
      *(uint4*)(Bs + row * 32 + kq) = *(const uint4*)(W + (size_t)(n0 + row) * 1024 + kc + kq);
    }
    __syncthreads();
    short8v a[4], bb[4];
    #pragma unroll
    for (int mi = 0; mi < 4; mi++) a[mi]  = *(const short8v*)(As + (wm + mi * 16 + lr) * 32 + lk * 8);
    #pragma unroll
    for (int ni = 0; ni < 4; ni++) bb[ni] = *(const short8v*)(Bs + (wn + ni * 16 + lr) * 32 + lk * 8);
    #pragma unroll
    for (int mi = 0; mi < 4; mi++)
      #pragma unroll
      for (int ni = 0; ni < 4; ni++)
        acc[mi][ni] = MFMA16(a[mi], bb[ni], acc[mi][ni]);
  }
  #pragma unroll
  for (int mi = 0; mi < 4; mi++)
    #pragma unroll
    for (int ni = 0; ni < 4; ni++)
      #pragma unroll
      for (int r = 0; r < 4; r++){
        int row = m0 + wm + mi * 16 + lk * 4 + r;
        int col = n0 + wn + ni * 16 + lr;
        C[(size_t)row * 1024 + col] = f2bf(acc[mi][ni][r] + bias[col]);
      }
}

// ---------------- K GEMM (transposed out): Kt[b][hd][s] = (Wk @ comp_b^T) + bk ----------------
__global__ __launch_bounds__(256) void gemmk_k(const float* __restrict__ A,
    const u16* __restrict__ W, const float* __restrict__ bias, u16* __restrict__ Kt)
{
  int n0 = blockIdx.x * 128;   // cols over (b,s)
  int m0 = blockIdx.y * 128;   // rows over (h,d)
  __shared__ u16 Ws[128 * 32];   // W rows (m side)
  __shared__ u16 Cs[128 * 32];   // comp rows (n side)
  int tid = threadIdx.x;
  int w = tid >> 6, l = tid & 63, lr = l & 15, lk = l >> 4;
  int wm = (w >> 1) * 64, wn = (w & 1) * 64;
  f32x4 acc[4][4];
  #pragma unroll
  for (int i = 0; i < 4; i++)
    #pragma unroll
    for (int j = 0; j < 4; j++) acc[i][j] = (f32x4){0.f,0.f,0.f,0.f};

  for (int kc = 0; kc < 1024; kc += 32){
    __syncthreads();
    #pragma unroll
    for (int u = 0; u < 2; u++){            // stage W (bf16)
      int i = tid + u * 256;
      int row = i >> 2, kq = (i & 3) * 8;
      *(uint4*)(Ws + row * 32 + kq) = *(const uint4*)(W + (size_t)(m0 + row) * 1024 + kc + kq);
    }
    #pragma unroll
    for (int u = 0; u < 4; u++){            // stage comp (fp32 -> bf16)
      int i = tid + u * 256;
      int row = i >> 3, kq = (i & 7) * 4;
      float4 v = *(const float4*)(A + (size_t)(n0 + row) * 1024 + kc + kq);
      uint2 pk;
      pk.x = (u32)f2bf(v.x) | ((u32)f2bf(v.y) << 16);
      pk.y = (u32)f2bf(v.z) | ((u32)f2bf(v.w) << 16);
      *(uint2*)(Cs + row * 32 + kq) = pk;
    }
    __syncthreads();
    short8v a[4], bb[4];
    #pragma unroll
    for (int mi = 0; mi < 4; mi++) a[mi]  = *(const short8v*)(Ws + (wm + mi * 16 + lr) * 32 + lk * 8);
    #pragma unroll
    for (int ni = 0; ni < 4; ni++) bb[ni] = *(const short8v*)(Cs + (wn + ni * 16 + lr) * 32 + lk * 8);
    #pragma unroll
    for (int mi = 0; mi < 4; mi++)
      #pragma unroll
      for (int ni = 0; ni < 4; ni++)
        acc[mi][ni] = MFMA16(a[mi], bb[ni], acc[mi][ni]);
  }
  #pragma unroll
  for (int mi = 0; mi < 4; mi++)
    #pragma unroll
    for (int ni = 0; ni < 4; ni++)
      #pragma unroll
      for (int r = 0; r < 4; r++){
        int row = m0 + wm + mi * 16 + lk * 4 + r;       // hd
        int col = n0 + wn + ni * 16 + lr;               // b*1024 + s
        int b = col >> 10, s = col & 1023;
        Kt[((size_t)b * 1024 + row) * 1024 + s] = f2bf(acc[mi][ni][r] + bias[row]);
      }
}

// ---------------- multi-segment M=32 MFMA linear ----------------
struct LinSeg {
  const float* X0; const float* Xa; const float* Xb; const float* Xc;  // summed A inputs
  const u16* W1; const float* b1;
  const float* Y; const u16* W2; const float* b2;                     // optional 2nd GEMM
  float* out; float* out2;
  int K1, ld1, K2, ld2, N, act;   // act: 0 none, 1 gelu, 2 scale
  float scale;
};

__device__ __forceinline__ short8v load_sum8(const LinSeg& S, int row, int kb){
  size_t o = (size_t)row * S.K1 + kb;
  float4 v0 = *(const float4*)(S.X0 + o);
  float4 v1 = *(const float4*)(S.X0 + o + 4);
  if (S.Xa){ acc4(v0, *(const float4*)(S.Xa + o)); acc4(v1, *(const float4*)(S.Xa + o + 4)); }
  if (S.Xb){ acc4(v0, *(const float4*)(S.Xb + o)); acc4(v1, *(const float4*)(S.Xb + o + 4)); }
  if (S.Xc){ acc4(v0, *(const float4*)(S.Xc + o)); acc4(v1, *(const float4*)(S.Xc + o + 4)); }
  short8v r;
  r[0]=(short)f2bf(v0.x); r[1]=(short)f2bf(v0.y); r[2]=(short)f2bf(v0.z); r[3]=(short)f2bf(v0.w);
  r[4]=(short)f2bf(v1.x); r[5]=(short)f2bf(v1.y); r[6]=(short)f2bf(v1.z); r[7]=(short)f2bf(v1.w);
  return r;
}
__device__ __forceinline__ short8v load_y8(const float* __restrict__ p){
  float4 v0 = *(const float4*)(p);
  float4 v1 = *(const float4*)(p + 4);
  short8v r;
  r[0]=(short)f2bf(v0.x); r[1]=(short)f2bf(v0.y); r[2]=(short)f2bf(v0.z); r[3]=(short)f2bf(v0.w);
  r[4]=(short)f2bf(v1.x); r[5]=(short)f2bf(v1.y); r[6]=(short)f2bf(v1.z); r[7]=(short)f2bf(v1.w);
  return r;
}

typedef float Red32[32][32];

__device__ void lin_body(const LinSeg& S, int bi, int tid, Red32* red){
  int c0 = bi * 32;
  int w = tid >> 6, l = tid & 63, lr = l & 15, lk = l >> 4;
  f32x4 acc[2][2];
  #pragma unroll
  for (int i = 0; i < 2; i++)
    #pragma unroll
    for (int j = 0; j < 2; j++) acc[i][j] = (f32x4){0.f,0.f,0.f,0.f};

  {
    int chunk = S.K1 >> 3;
    int kb0 = w * chunk + lk * 8;
    for (int kk = 0; kk < chunk; kk += 32){
      int kb = kb0 + kk;
      short8v a0 = load_sum8(S, lr, kb);
      short8v a1 = load_sum8(S, lr + 16, kb);
      short8v w0 = *(const short8v*)(S.W1 + (size_t)(c0 + lr) * S.ld1 + kb);
      short8v w1 = *(const short8v*)(S.W1 + (size_t)(c0 + lr + 16) * S.ld1 + kb);
      acc[0][0] = MFMA16(a0, w0, acc[0][0]);
      acc[0][1] = MFMA16(a0, w1, acc[0][1]);
      acc[1][0] = MFMA16(a1, w0, acc[1][0]);
      acc[1][1] = MFMA16(a1, w1, acc[1][1]);
    }
  }
  if (S.Y){
    int chunk = S.K2 >> 3;
    int kb0 = w * chunk + lk * 8;
    for (int kk = 0; kk < chunk; kk += 32){
      int kb = kb0 + kk;
      short8v a0 = load_y8(S.Y + (size_t)lr * S.K2 + kb);
      short8v a1 = load_y8(S.Y + (size_t)(lr + 16) * S.K2 + kb);
      short8v w0 = *(const short8v*)(S.W2 + (size_t)(c0 + lr) * S.ld2 + kb);
      short8v w1 = *(const short8v*)(S.W2 + (size_t)(c0 + lr + 16) * S.ld2 + kb);
      acc[0][0] = MFMA16(a0, w0, acc[0][0]);
      acc[0][1] = MFMA16(a0, w1, acc[0][1]);
      acc[1][0] = MFMA16(a1, w0, acc[1][0]);
      acc[1][1] = MFMA16(a1, w1, acc[1][1]);
    }
  }
  #pragma unroll
  for (int mi = 0; mi < 2; mi++)
    #pragma unroll
    for (int ni = 0; ni < 2; ni++)
      #pragma unroll
      for (int r = 0; r < 4; r++)
        red[w][mi * 16 + lk * 4 + r][ni * 16 + lr] = acc[mi][ni][r];
  __syncthreads();
  for (int i = tid; i < 1024; i += 512){
    int row = i >> 5, col = i & 31;
    float v = 0.f;
    #pragma unroll
    for (int ww = 0; ww < 8; ww++) v += red[ww][row][col];
    v += S.b1[c0 + col];
    if (S.b2) v += S.b2[c0 + col];
    if (S.act == 1) v = gelu_f(v);
    else if (S.act == 2) v *= S.scale;
    S.out[(size_t)row * S.N + c0 + col] = v;
    if (S.out2) S.out2[(size_t)row * S.N + c0 + col] = v;
  }
}

__global__ __launch_bounds__(512) void linmulti_k(LinSeg s0, LinSeg s1, LinSeg s2, int n0, int n1){
  __shared__ float red[8][32][32];
  int bx = blockIdx.x, tid = threadIdx.x;
  if (bx < n0) lin_body(s0, bx, tid, red);
  else if (bx < n0 + n1) lin_body(s1, bx - n0, tid, red);
  else lin_body(s2, bx - n0 - n1, tid, red);
}

// ---------------- rule2 (softmax+sel) fused with LSTM0 gates ----------------
__global__ __launch_bounds__(256) void rg0_k(
    const float* __restrict__ h1a, const float* __restrict__ w2, const float* __restrict__ b2,
    const float* __restrict__ emb, float* __restrict__ probs_out, float* __restrict__ sel,
    const float* __restrict__ g, const float* __restrict__ cprev,
    float* __restrict__ cn, float* __restrict__ hn)
{
  int tid = threadIdx.x;
  if (blockIdx.x < 128){
    int idx = blockIdx.x * 256 + tid;
    int b = idx >> 10, j = idx & 1023;
    const float* gr = g + (size_t)b * 4096;
    float gi = gr[j], gf = gr[1024 + j], gg = gr[2048 + j], go = gr[3072 + j];
    float c = sigm_f(gf) * cprev[idx] + sigm_f(gi) * tanhf(gg);
    cn[idx] = c;
    hn[idx] = sigm_f(go) * tanhf(c);
    return;
  }
  int b = blockIdx.x - 128;
  __shared__ float lg[32], pshared[32];
  int j = tid >> 3, l8 = tid & 7;
  const float* xr = h1a + b * 1024;
  const float* wr = w2 + j * 1024;
  float acc = 0.f;
  #pragma unroll 8
  for (int kk = 0; kk < 32; kk++){
    int k = kk * 32 + l8 * 4;
    float4 xv = *(const float4*)(xr + k);
    float4 wv = *(const float4*)(wr + k);
    acc += xv.x * wv.x + xv.y * wv.y + xv.z * wv.z + xv.w * wv.w;
  }
  acc += __shfl_xor(acc, 1); acc += __shfl_xor(acc, 2); acc += __shfl_xor(acc, 4);
  if (l8 == 0) lg[j] = acc + b2[j];
  __syncthreads();
  if (tid < 32){
    float v = lg[tid];
    float m = v;
    for (int o = 1; o < 32; o <<= 1) m = fmaxf(m, __shfl_xor(m, o));
    float e = __expf(v - m);
    float s = e;
    for (int o = 1; o < 32; o <<= 1) s += __shfl_xor(s, o);
    float p = e / s;
    pshared[tid] = p;
    probs_out[b * 32 + tid] = p;
  }
  __syncthreads();
  for (int j2 = tid; j2 < 1024; j2 += 256){
    float a2 = 0.f;
    #pragma unroll
    for (int r = 0; r < 32; r++) a2 += pshared[r] * emb[r * 1024 + j2];
    sel[b * 1024 + j2] = a2;
  }
}

// ---------------- attention with Kt layout, one block per (b,h) ----------------
__global__ __launch_bounds__(256) void attn_k(const float* __restrict__ q,
    const u16* __restrict__ Kt, const u16* __restrict__ Vb,
    float* __restrict__ afull, float* __restrict__ ctx0)
{
  int bh = blockIdx.x;                 // b*16 + h
  int b = bh >> 4, h = bh & 15;
  int tid = threadIdx.x;
  __shared__ float qs[64];
  __shared__ float sc[1024];
  __shared__ float rmx[4], rsm[4];
  __shared__ float ctxp[8][64];
  if (tid < 64) qs[tid] = q[bh * 64 + tid];
  __syncthreads();
  const u32* kt = (const u32*)(Kt + (size_t)bh * 65536);   // [d][s/2] pairs
  float a0 = 0.f, a1 = 0.f, a2 = 0.f, a3 = 0.f;
  #pragma unroll 8
  for (int d = 0; d < 64; d++){
    float qd = qs[d];
    u32 p0 = kt[d * 512 + tid];
    u32 p1 = kt[d * 512 + tid + 256];
    a0 += qd * bf2f((u16)(p0 & 0xffff)); a1 += qd * bf2f((u16)(p0 >> 16));
    a2 += qd * bf2f((u16)(p1 & 0xffff)); a3 += qd * bf2f((u16)(p1 >> 16));
  }
  float mx = fmaxf(fmaxf(a0, a1), fmaxf(a2, a3));
  for (int o = 1; o < 64; o <<= 1) mx = fmaxf(mx, __shfl_xor(mx, o));
  if ((tid & 63) == 0) rmx[tid >> 6] = mx;
  __syncthreads();
  mx = fmaxf(fmaxf(rmx[0], rmx[1]), fmaxf(rmx[2], rmx[3]));
  float e0 = __expf(a0 - mx), e1 = __expf(a1 - mx), e2 = __expf(a2 - mx), e3 = __expf(a3 - mx);
  float sm = e0 + e1 + e2 + e3;
  for (int o = 1; o < 64; o <<= 1) sm += __shfl_xor(sm, o);
  if ((tid & 63) == 0) rsm[tid >> 6] = sm;
  __syncthreads();
  sm = rsm[0] + rsm[1] + rsm[2] + rsm[3];
  float inv = 1.f / sm;
  float* ar = afull + (size_t)bh * 1024;
  float2 w0 = make_float2(e0 * inv, e1 * inv);
  float2 w1 = make_float2(e2 * inv, e3 * inv);
  *(float2*)(sc + 2 * tid) = w0;       *(float2*)(ar + 2 * tid) = w0;
  *(float2*)(sc + 512 + 2 * tid) = w1; *(float2*)(ar + 512 + 2 * tid) = w1;
  __syncthreads();
  int d2 = (tid & 31) * 2, chunk = tid >> 5;        // 8 chunks of 128 s
  const u16* vb = Vb + ((size_t)(b * 1024) * 16 + h) * 64 + d2;
  float c0 = 0.f, c1 = 0.f;
  for (int s = chunk * 128; s < chunk * 128 + 128; s++){
    u32 vv = *(const u32*)(vb + (size_t)s * 1024);
    float wv = sc[s];
    c0 += wv * bf2f((u16)(vv & 0xffff));
    c1 += wv * bf2f((u16)(vv >> 16));
  }
  *(float2*)&ctxp[chunk][d2] = make_float2(c0, c1);
  __syncthreads();
  if (tid < 64){
    float r = 0.f;
    #pragma unroll
    for (int c = 0; c < 8; c++) r += ctxp[c][tid];
    ctx0[bh * 64 + tid] = r;
  }
}

// ---------------- LSTM1 gates fused with attn head-mean ----------------
__global__ __launch_bounds__(256) void ga1_k(const float* __restrict__ g, const float* __restrict__ cprev,
                                             float* __restrict__ cn, float* __restrict__ hn,
                                             const float* __restrict__ afull, float* __restrict__ aout){
  int idx = blockIdx.x * 256 + threadIdx.x;     // 32768
  int b = idx >> 10, j = idx & 1023;
  const float* gr = g + (size_t)b * 4096;
  float gi = gr[j], gf = gr[1024 + j], gg = gr[2048 + j], go = gr[3072 + j];
  float c = sigm_f(gf) * cprev[idx] + sigm_f(gi) * tanhf(gg);
  cn[idx] = c;
  hn[idx] = sigm_f(go) * tanhf(c);
  float acc = 0.f;
  #pragma unroll
  for (int hh = 0; hh < 16; hh++) acc += afull[((size_t)(b * 16 + hh)) * 1024 + j];
  aout[idx] = acc * (1.f / 16.f);
}

// ---------------- layernorm(2048) + gelu, one block per row ----------------
__global__ __launch_bounds__(256) void lngelu_k(const float* __restrict__ z, const float* __restrict__ g,
                                                const float* __restrict__ bta, float* __restrict__ zg){
  int bb = blockIdx.x, tid = threadIdx.x;
  const float* zr = z + (size_t)bb * 2048;
  float v[8]; float s = 0.f;
  #pragma unroll
  for (int i = 0; i < 8; i++){ v[i] = zr[tid + i * 256]; s += v[i]; }
  __shared__ float red[4], red2[4];
  for (int o = 1; o < 64; o <<= 1) s += __shfl_xor(s, o);
  if ((tid & 63) == 0) red[tid >> 6] = s;
  __syncthreads();
  float mu = (red[0] + red[1] + red[2] + red[3]) * (1.f / 2048.f);
  float s2 = 0.f;
  #pragma unroll
  for (int i = 0; i < 8; i++){ float d = v[i] - mu; s2 += d * d; }
  for (int o = 1; o < 64; o <<= 1) s2 += __shfl_xor(s2, o);
  if ((tid & 63) == 0) red2[tid >> 6] = s2;
  __syncthreads();
  float var = (red2[0] + red2[1] + red2[2] + red2[3]) * (1.f / 2048.f);
  float rstd = rsqrtf(var + 1e-5f);
  float* zo = zg + (size_t)bb * 2048;
  #pragma unroll
  for (int i = 0; i < 8; i++){
    int idx = tid + i * 256;
    float y = (v[i] - mu) * rstd * g[idx] + bta[idx];
    zo[idx] = gelu_f(y);
  }
}

// ---------------- 32 rows dot w (K=1024) -> sigmoid ----------------
__global__ __launch_bounds__(256) void dotsig_k(const float* __restrict__ x, const float* __restrict__ w,
                                                const float* __restrict__ bias, float* __restrict__ out){
  int b = threadIdx.x >> 3, l8 = threadIdx.x & 7;
  const float* xr = x + (size_t)b * 1024;
  float acc = 0.f;
  #pragma unroll 8
  for (int kk = 0; kk < 32; kk++){
    int k = kk * 32 + l8 * 4;
    float4 xv = *(const float4*)(xr + k);
    float4 wv = *(const float4*)(w + k);
    acc += xv.x * wv.x + xv.y * wv.y + xv.z * wv.z + xv.w * wv.w;
  }
  acc += __shfl_xor(acc, 1); acc += __shfl_xor(acc, 2); acc += __shfl_xor(acc, 4);
  if (l8 == 0) out[b] = sigm_f(acc + bias[0]);
}

extern "C" void kernel_launch(void* const* d_in, const int* in_sizes, int n_in,
                              void* d_out, int out_size, void* d_ws, size_t ws_size,
                              hipStream_t stream) {
  const float* comp      = (const float*)d_in[0];
  const float* rule_w1   = (const float*)d_in[2];
  const float* rule_b1   = (const float*)d_in[3];
  const float* rule_w2   = (const float*)d_in[4];
  const float* rule_b2   = (const float*)d_in[5];
  const float* rule_emb  = (const float*)d_in[6];
  const float* attn_in_w = (const float*)d_in[7];
  const float* attn_in_b = (const float*)d_in[8];
  const float* attn_out_w= (const float*)d_in[9];
  const float* attn_out_b= (const float*)d_in[10];
  const float* wih0 = (const float*)d_in[11];
  const float* whh0 = (const float*)d_in[12];
  const float* bih0 = (const float*)d_in[13];
  const float* bhh0 = (const float*)d_in[14];
  const float* wih1 = (const float*)d_in[15];
  const float* whh1 = (const float*)d_in[16];
  const float* bih1 = (const float*)d_in[17];
  const float* bhh1 = (const float*)d_in[18];
  const float* gen_w1 = (const float*)d_in[19];
  const float* gen_b1 = (const float*)d_in[20];
  const float* ln_g   = (const float*)d_in[21];
  const float* ln_b   = (const float*)d_in[22];
  const float* gen_w2 = (const float*)d_in[23];
  const float* gen_b2 = (const float*)d_in[24];
  const float* val_w1 = (const float*)d_in[25];
  const float* val_b1 = (const float*)d_in[26];
  const float* val_w2 = (const float*)d_in[27];
  const float* val_b2 = (const float*)d_in[28];
  const float* ver_w1 = (const float*)d_in[29];
  const float* ver_b1 = (const float*)d_in[30];
  const float* ver_w2 = (const float*)d_in[31];
  const float* ver_b2 = (const float*)d_in[32];

  float* out_f     = (float*)d_out;
  float* out_proof = out_f;                       // (17,32,1024)
  float* out_valid = out_f + 17 * 32768;          // (32,1)
  float* out_probs = out_valid + 32;              // (16,32,32)
  float* out_vals  = out_probs + 16 * 1024;       // (16,32,1)
  float* out_attn  = out_vals + 16 * 32;          // (16,32,1024)

  char* wp = (char*)d_ws;
  auto carve = [&](size_t bytes) -> void* {
    void* p = (void*)wp; wp += (bytes + 255) & ~(size_t)255; return p;
  };
  u16* Kt    = (u16*)carve((size_t)33554432 * 2);   // [b][hd][s]
  u16* Vb    = (u16*)carve((size_t)33554432 * 2);   // [b][s][hd]
  u16* rw1b  = (u16*)carve(2097152);
  u16* wqb   = (u16*)carve(2097152);
  u16* wkb   = (u16*)carve(2097152);
  u16* wvb   = (u16*)carve(2097152);
  u16* aowb  = (u16*)carve(2097152);
  u16* wih0b = (u16*)carve(8388608);
  u16* whh0b = (u16*)carve(8388608);
  u16* wih1b = (u16*)carve(8388608);
  u16* whh1b = (u16*)carve(8388608);
  u16* gw1b  = (u16*)carve(4194304);
  u16* gw2b  = (u16*)carve(4194304);
  u16* vw1b  = (u16*)carve(4194304);
  u16* verw1b= (u16*)carve(2097152);
  float* psb[2]  = { (float*)carve(131072), (float*)carve(131072) };
  float* h0b[2]  = { (float*)carve(131072), (float*)carve(131072) };
  float* c0b[2]  = { (float*)carve(131072), (float*)carve(131072) };
  float* h1b[2]  = { (float*)carve(131072), (float*)carve(131072) };
  float* c1b[2]  = { (float*)carve(131072), (float*)carve(131072) };
  float* h1act = (float*)carve(131072);
  float* sel   = (float*)carve(131072);
  float* qbuf  = (float*)carve(131072);
  float* ctx0  = (float*)carve(131072);
  float* ctxb  = (float*)carve(131072);
  float* v1buf = (float*)carve(131072);
  float* gbuf  = (float*)carve(524288);
  float* zbuf  = (float*)carve(262144);
  float* zgbuf = (float*)carve(262144);
  float* afull = (float*)carve(2097152);
  (void)ws_size; (void)in_sizes; (void)n_in; (void)out_size;

  // ---- fused weight casts ----
  CastJobs J;
  const float* srcs[13] = { rule_w1, attn_in_w, attn_in_w + 1048576, attn_in_w + 2097152,
                            attn_out_w, wih0, whh0, wih1, whh1, gen_w1, gen_w2, val_w1, ver_w1 };
  u16* dsts[13] = { rw1b, wqb, wkb, wvb, aowb, wih0b, whh0b, wih1b, whh1b, gw1b, gw2b, vw1b, verw1b };
  int sizes[13] = { 1048576, 1048576, 1048576, 1048576, 1048576,
                    4194304, 4194304, 4194304, 4194304, 2097152, 2097152, 2097152, 1048576 };
  int st = 0;
  for (int i = 0; i < 13; i++){ J.s[i] = srcs[i]; J.d[i] = dsts[i]; J.start[i] = st; st += sizes[i] / 1024; }
  J.start[13] = st;
  cast_all_k<<<dim3(st), dim3(256), 0, stream>>>(J);

  gemmk_k<<<dim3(256, 8), dim3(256), 0, stream>>>(comp, wkb, attn_in_b + 1024, Kt);
  gemmv_k<<<dim3(256, 8), dim3(256), 0, stream>>>(comp, wvb, attn_in_b + 2048, Vb);

  init_k<<<dim3(128), dim3(256), 0, stream>>>(comp, psb[0], out_proof,
      h0b[0], c0b[0], h1b[0], c1b[0]);

  auto mkseg = [&](const float* X0, const float* Xa, const float* Xb, const float* Xc,
                   int K1, const u16* W1, int ld1, const float* bb1,
                   const float* Y, int K2, const u16* W2, int ld2, const float* bb2,
                   float* out, int N, int act, float scl, float* out2) -> LinSeg {
    LinSeg S; S.X0 = X0; S.Xa = Xa; S.Xb = Xb; S.Xc = Xc; S.K1 = K1; S.W1 = W1; S.ld1 = ld1; S.b1 = bb1;
    S.Y = Y; S.K2 = K2; S.W2 = W2; S.ld2 = ld2; S.b2 = bb2;
    S.out = out; S.N = N; S.act = act; S.scale = scl; S.out2 = out2;
    return S;
  };
  auto lin1 = [&](LinSeg S){
    linmulti_k<<<dim3(S.N / 32), dim3(512), 0, stream>>>(S, S, S, S.N / 32, 0);
  };

  for (int t = 0; t < 16; t++){
    int cur = t & 1, nx = cur ^ 1;
    float* ps = psb[cur];
    // mega1: rule h1 (gelu), q (scaled), lstm0 gates
    LinSeg sRule = mkseg(ps, 0, 0, 0, 1024, rw1b, 1024, rule_b1, 0, 0, 0, 0, 0, h1act, 1024, 1, 0.f, 0);
    LinSeg sQ    = mkseg(ps, 0, 0, 0, 1024, wqb, 1024, attn_in_b, 0, 0, 0, 0, 0, qbuf, 1024, 2, 0.125f, 0);
    LinSeg sL0   = mkseg(ps, 0, 0, 0, 1024, wih0b, 1024, bih0, h0b[cur], 1024, whh0b, 1024, bhh0,
                         gbuf, 4096, 0, 0.f, 0);
    linmulti_k<<<dim3(192), dim3(512), 0, stream>>>(sRule, sQ, sL0, 32, 32);
    // attention
    attn_k<<<dim3(512), dim3(256), 0, stream>>>(qbuf, Kt, Vb, afull, ctx0);
    // rule2 softmax+sel  +  lstm0 gates
    rg0_k<<<dim3(160), dim3(256), 0, stream>>>(h1act, rule_w2, rule_b2, rule_emb,
        out_probs + t * 1024, sel, gbuf, c0b[cur], c0b[nx], h0b[nx]);
    // mega2: ctx proj + lstm1 gates GEMM
    LinSeg sCtx = mkseg(ctx0, 0, 0, 0, 1024, aowb, 1024, attn_out_b, 0, 0, 0, 0, 0, ctxb, 1024, 0, 0.f, 0);
    LinSeg sL1  = mkseg(h0b[nx], 0, 0, 0, 1024, wih1b, 1024, bih1, h1b[cur], 1024, whh1b, 1024, bhh1,
                        gbuf, 4096, 0, 0.f, 0);
    linmulti_k<<<dim3(160), dim3(512), 0, stream>>>(sCtx, sL1, sL1, 32, 128);
    // lstm1 gates + attn head-mean
    ga1_k<<<dim3(128), dim3(256), 0, stream>>>(gbuf, c1b[cur], c1b[nx], h1b[nx],
        afull, out_attn + (size_t)t * 32768);
    // generator: z = (ps+sel+ctx+mem) @ gw1^T + b   (sum4 fused into A-load)
    LinSeg sG1 = mkseg(ps, sel, ctxb, h1b[nx], 1024, gw1b, 1024, gen_b1, 0, 0, 0, 0, 0,
                       zbuf, 2048, 0, 0.f, 0);
    lin1(sG1);
    lngelu_k<<<dim3(32), dim3(256), 0, stream>>>(zbuf, ln_g, ln_b, zgbuf);
    LinSeg sG2 = mkseg(zgbuf, 0, 0, 0, 2048, gw2b, 2048, gen_b2, 0, 0, 0, 0, 0,
                       psb[nx], 1024, 0, 0.f, out_proof + (size_t)(t + 1) * 32768);
    lin1(sG2);
    // value head
    LinSeg sV = mkseg(ps, 0, 0, 0, 1024, vw1b, 2048, val_b1, psb[nx], 1024, vw1b + 1024, 2048, 0,
                      v1buf, 1024, 1, 0.f, 0);
    lin1(sV);
    dotsig_k<<<dim3(1), dim3(256), 0, stream>>>(v1buf, val_w2, val_b2, out_vals + t * 32);
  }
  // verifier (final state is psb[0] after 16 steps)
  LinSeg sVer = mkseg(psb[0], 0, 0, 0, 1024, verw1b, 1024, ver_b1, 0, 0, 0, 0, 0,
                      v1buf, 1024, 1, 0.f, 0);
  lin1(sVer);
  dotsig_k<<<dim3(1), dim3(256), 0, stream>>>(v1buf, ver_w2, ver_b2, out_valid);
}

// Round 3
// 1948.470 us; speedup vs baseline: 1.3124x; 1.1394x over previous
//
#include <hip/hip_runtime.h>

typedef unsigned short u16;
typedef unsigned int u32;
typedef __attribute__((ext_vector_type(8))) short short8v;   // 8 bf16 (4 VGPRs)
typedef __attribute__((ext_vector_type(4))) float f32x4;

#define MFMA16(a,b,c) __builtin_amdgcn_mfma_f32_16x16x32_bf16((a),(b),(c),0,0,0)

__device__ __forceinline__ u16 f2bf(float f){
  u32 u = __float_as_uint(f);
  return (u16)((u + 0x7fffu + ((u >> 16) & 1u)) >> 16);   // RNE
}
__device__ __forceinline__ float bf2f(u16 h){ return __uint_as_float(((u32)h) << 16); }
__device__ __forceinline__ float gelu_f(float x){ return 0.5f * x * (1.f + erff(x * 0.70710678118654752f)); }
__device__ __forceinline__ float sigm_f(float x){ return 1.f / (1.f + __expf(-x)); }
__device__ __forceinline__ void acc4(float4& a, const float4 b){ a.x+=b.x; a.y+=b.y; a.z+=b.z; a.w+=b.w; }

// async global->LDS, 16B per lane (HW: wave-uniform LDS base + lane*16)
__device__ __forceinline__ void gl16(const void* g, void* l){
  __builtin_amdgcn_global_load_lds((const __attribute__((address_space(1))) u32*)g,
                                   (__attribute__((address_space(3))) u32*)l, 16, 0, 0);
}

// ---------------- fused weight cast fp32 -> bf16 (13 jobs, one launch) ----------------
struct CastJobs { const float* s[13]; u16* d[13]; int start[14]; };
__global__ __launch_bounds__(256) void cast_all_k(CastJobs J){
  int bx = blockIdx.x, j = 0;
  #pragma unroll
  for (int t = 0; t < 13; t++) if (bx >= J.start[t + 1]) j = t + 1;
  int i = (bx - J.start[j]) * 1024 + threadIdx.x * 4;
  float4 v = *(const float4*)(J.s[j] + i);
  ushort4 o; o.x = f2bf(v.x); o.y = f2bf(v.y); o.z = f2bf(v.z); o.w = f2bf(v.w);
  *(ushort4*)(J.d[j] + i) = o;
}

__global__ __launch_bounds__(256) void cast_k(const float* __restrict__ s, u16* __restrict__ d, int n){
  int i = (blockIdx.x * 256 + threadIdx.x) * 4;
  if (i + 3 < n){
    float4 v = *(const float4*)(s + i);
    ushort4 o; o.x = f2bf(v.x); o.y = f2bf(v.y); o.z = f2bf(v.z); o.w = f2bf(v.w);
    *(ushort4*)(d + i) = o;
  }
}

// ---------------- init ----------------
__global__ __launch_bounds__(256) void init_k(const float* __restrict__ comp, float* ps0, float* outp,
                                              float* h0, float* c0, float* h1, float* c1){
  int i = blockIdx.x * 256 + threadIdx.x;       // 32768
  int b = i >> 10, hh = i & 1023;
  float v = comp[(size_t)b * 1048576 + hh];
  ps0[i] = v; outp[i] = v;
  h0[i] = 0.f; c0[i] = 0.f; h1[i] = 0.f; c1[i] = 0.f;
}

// ---------------- fused K/V GEMM (bf16 in, global_load_lds staging, m97 structure) ----------------
// z=0: V[bs][hd] = compb @ Wv^T + bv          (m over comp rows, n over Wv rows)
// z=1: Kt[b][hd][s] = Wk @ compb^T + bk       (m over Wk rows, n over comp rows)
__global__ __launch_bounds__(256) void gemmkv_k(const u16* __restrict__ compb,
    const u16* __restrict__ Wk, const u16* __restrict__ Wv,
    const float* __restrict__ bk, const float* __restrict__ bv,
    u16* __restrict__ Kt, u16* __restrict__ Vb)
{
  __shared__ u16 As[128 * 32];
  __shared__ u16 Bs[128 * 32];
  int tid = threadIdx.x;
  const u16 *msrc, *nsrc;
  int m0, n0, isK = (blockIdx.z != 0);
  if (!isK){ m0 = blockIdx.x * 128; n0 = blockIdx.y * 128; msrc = compb; nsrc = Wv; }
  else     { m0 = blockIdx.y * 128; n0 = blockIdx.x * 128; msrc = Wk;    nsrc = compb; }

  int w = tid >> 6, l = tid & 63, lr = l & 15, lk = l >> 4;
  int wm = (w >> 1) * 64, wn = (w & 1) * 64;
  f32x4 acc[4][4];
  #pragma unroll
  for (int i = 0; i < 4; i++)
    #pragma unroll
    for (int j = 0; j < 4; j++) acc[i][j] = (f32x4){0.f,0.f,0.f,0.f};

  int row0 = tid >> 2, k80 = (tid & 3) * 8;        // staging decomposition
  for (int kc = 0; kc < 1024; kc += 32){
    #pragma unroll
    for (int r = 0; r < 2; r++){
      int i = tid + r * 256;
      int row = row0 + r * 64, k8 = k80;
      gl16(msrc + (size_t)(m0 + row) * 1024 + kc + k8, As + i * 8);
      gl16(nsrc + (size_t)(n0 + row) * 1024 + kc + k8, Bs + i * 8);
    }
    __syncthreads();                                // drains vmcnt before barrier
    short8v a[4], bb[4];
    #pragma unroll
    for (int mi = 0; mi < 4; mi++) a[mi]  = *(const short8v*)(As + (wm + mi * 16 + lr) * 32 + lk * 8);
    #pragma unroll
    for (int ni = 0; ni < 4; ni++) bb[ni] = *(const short8v*)(Bs + (wn + ni * 16 + lr) * 32 + lk * 8);
    #pragma unroll
    for (int mi = 0; mi < 4; mi++)
      #pragma unroll
      for (int ni = 0; ni < 4; ni++)
        acc[mi][ni] = MFMA16(a[mi], bb[ni], acc[mi][ni]);
    __syncthreads();                                // protect LDS before next overwrite
  }
  #pragma unroll
  for (int mi = 0; mi < 4; mi++)
    #pragma unroll
    for (int ni = 0; ni < 4; ni++)
      #pragma unroll
      for (int r = 0; r < 4; r++){
        int row = m0 + wm + mi * 16 + lk * 4 + r;
        int col = n0 + wn + ni * 16 + lr;
        if (!isK){
          Vb[(size_t)row * 1024 + col] = f2bf(acc[mi][ni][r] + bv[col]);
        } else {
          int b = col >> 10, s = col & 1023;        // col over (b,s); row over hd
          Kt[((size_t)b * 1024 + row) * 1024 + s] = f2bf(acc[mi][ni][r] + bk[row]);
        }
      }
}

// ---------------- multi-segment M=32 MFMA linear ----------------
struct LinSeg {
  const float* X0; const float* Xa; const float* Xb; const float* Xc;  // summed A inputs
  const u16* W1; const float* b1;
  const float* Y; const u16* W2; const float* b2;                     // optional 2nd GEMM
  float* out; float* out2;
  int K1, ld1, K2, ld2, N, act;   // act: 0 none, 1 gelu, 2 scale
  float scale;
  float* stats;                   // if set: epilogue accumulates row sum/sumsq (atomics)
  const float* lng; const float* lnb; const float* lnstats;  // if lng set: LN+gelu on A-load
};

__device__ __forceinline__ short8v pack8(float4 v0, float4 v1){
  short8v r;
  r[0]=(short)f2bf(v0.x); r[1]=(short)f2bf(v0.y); r[2]=(short)f2bf(v0.z); r[3]=(short)f2bf(v0.w);
  r[4]=(short)f2bf(v1.x); r[5]=(short)f2bf(v1.y); r[6]=(short)f2bf(v1.z); r[7]=(short)f2bf(v1.w);
  return r;
}

__device__ __forceinline__ short8v load_sum8(const LinSeg& S, int row, int kb){
  size_t o = (size_t)row * S.K1 + kb;
  float4 v0 = *(const float4*)(S.X0 + o);
  float4 v1 = *(const float4*)(S.X0 + o + 4);
  if (S.lng){
    float mu = S.lnstats[row] * (1.f / 2048.f);
    float ms = S.lnstats[32 + row] * (1.f / 2048.f);
    float rstd = rsqrtf(ms - mu * mu + 1e-5f);
    float4 g0 = *(const float4*)(S.lng + kb), g1 = *(const float4*)(S.lng + kb + 4);
    float4 b0 = *(const float4*)(S.lnb + kb), b1 = *(const float4*)(S.lnb + kb + 4);
    v0.x = gelu_f((v0.x - mu) * rstd * g0.x + b0.x);
    v0.y = gelu_f((v0.y - mu) * rstd * g0.y + b0.y);
    v0.z = gelu_f((v0.z - mu) * rstd * g0.z + b0.z);
    v0.w = gelu_f((v0.w - mu) * rstd * g0.w + b0.w);
    v1.x = gelu_f((v1.x - mu) * rstd * g1.x + b1.x);
    v1.y = gelu_f((v1.y - mu) * rstd * g1.y + b1.y);
    v1.z = gelu_f((v1.z - mu) * rstd * g1.z + b1.z);
    v1.w = gelu_f((v1.w - mu) * rstd * g1.w + b1.w);
  } else {
    if (S.Xa){ acc4(v0, *(const float4*)(S.Xa + o)); acc4(v1, *(const float4*)(S.Xa + o + 4)); }
    if (S.Xb){ acc4(v0, *(const float4*)(S.Xb + o)); acc4(v1, *(const float4*)(S.Xb + o + 4)); }
    if (S.Xc){ acc4(v0, *(const float4*)(S.Xc + o)); acc4(v1, *(const float4*)(S.Xc + o + 4)); }
  }
  return pack8(v0, v1);
}
__device__ __forceinline__ short8v load_y8(const float* __restrict__ p){
  return pack8(*(const float4*)(p), *(const float4*)(p + 4));
}

typedef float Red32[32][32];

__device__ void lin_body(const LinSeg& S, int bi, int tid, Red32* red){
  int c0 = bi * 32;
  int w = tid >> 6, l = tid & 63, lr = l & 15, lk = l >> 4;
  f32x4 acc[2][2];
  #pragma unroll
  for (int i = 0; i < 2; i++)
    #pragma unroll
    for (int j = 0; j < 2; j++) acc[i][j] = (f32x4){0.f,0.f,0.f,0.f};

  {
    int chunk = S.K1 >> 3;
    int kb0 = w * chunk + lk * 8;
    for (int kk = 0; kk < chunk; kk += 32){
      int kb = kb0 + kk;
      short8v a0 = load_sum8(S, lr, kb);
      short8v a1 = load_sum8(S, lr + 16, kb);
      short8v w0 = *(const short8v*)(S.W1 + (size_t)(c0 + lr) * S.ld1 + kb);
      short8v w1 = *(const short8v*)(S.W1 + (size_t)(c0 + lr + 16) * S.ld1 + kb);
      acc[0][0] = MFMA16(a0, w0, acc[0][0]);
      acc[0][1] = MFMA16(a0, w1, acc[0][1]);
      acc[1][0] = MFMA16(a1, w0, acc[1][0]);
      acc[1][1] = MFMA16(a1, w1, acc[1][1]);
    }
  }
  if (S.Y){
    int chunk = S.K2 >> 3;
    int kb0 = w * chunk + lk * 8;
    for (int kk = 0; kk < chunk; kk += 32){
      int kb = kb0 + kk;
      short8v a0 = load_y8(S.Y + (size_t)lr * S.K2 + kb);
      short8v a1 = load_y8(S.Y + (size_t)(lr + 16) * S.K2 + kb);
      short8v w0 = *(const short8v*)(S.W2 + (size_t)(c0 + lr) * S.ld2 + kb);
      short8v w1 = *(const short8v*)(S.W2 + (size_t)(c0 + lr + 16) * S.ld2 + kb);
      acc[0][0] = MFMA16(a0, w0, acc[0][0]);
      acc[0][1] = MFMA16(a0, w1, acc[0][1]);
      acc[1][0] = MFMA16(a1, w0, acc[1][0]);
      acc[1][1] = MFMA16(a1, w1, acc[1][1]);
    }
  }
  #pragma unroll
  for (int mi = 0; mi < 2; mi++)
    #pragma unroll
    for (int ni = 0; ni < 2; ni++)
      #pragma unroll
      for (int r = 0; r < 4; r++)
        red[w][mi * 16 + lk * 4 + r][ni * 16 + lr] = acc[mi][ni][r];
  __syncthreads();
  float vout[2]; int iout[2];
  int cnt = 0;
  for (int i = tid; i < 1024; i += 512){
    int row = i >> 5, col = i & 31;
    float v = 0.f;
    #pragma unroll
    for (int ww = 0; ww < 8; ww++) v += red[ww][row][col];
    v += S.b1[c0 + col];
    if (S.b2) v += S.b2[c0 + col];
    if (S.act == 1) v = gelu_f(v);
    else if (S.act == 2) v *= S.scale;
    S.out[(size_t)row * S.N + c0 + col] = v;
    if (S.out2) S.out2[(size_t)row * S.N + c0 + col] = v;
    vout[cnt] = v; iout[cnt] = i; cnt++;
  }
  if (S.stats){
    __syncthreads();
    float* rf = (float*)red;
    rf[iout[0]] = vout[0]; rf[1024 + iout[0]] = vout[0] * vout[0];
    rf[iout[1]] = vout[1]; rf[1024 + iout[1]] = vout[1] * vout[1];
    __syncthreads();
    if (tid < 32){
      float s = 0.f, s2 = 0.f;
      #pragma unroll
      for (int cc = 0; cc < 32; cc++){ s += rf[tid * 32 + cc]; s2 += rf[1024 + tid * 32 + cc]; }
      atomicAdd(S.stats + tid, s);
      atomicAdd(S.stats + 32 + tid, s2);
    }
  }
}

__global__ __launch_bounds__(512) void linmulti_k(LinSeg s0, LinSeg s1, LinSeg s2, int n0, int n1){
  __shared__ float red[8][32][32];
  int bx = blockIdx.x, tid = threadIdx.x;
  if (bx < n0) lin_body(s0, bx, tid, red);
  else if (bx < n0 + n1) lin_body(s1, bx - n0, tid, red);
  else lin_body(s2, bx - n0 - n1, tid, red);
}

// ---------------- batched value head (16 steps) + verifier, grid (32, 17) ----------------
__global__ __launch_bounds__(512) void valver_k(const u16* __restrict__ vw1, const float* __restrict__ vb1,
    const u16* __restrict__ verw1, const float* __restrict__ verb1,
    const float* __restrict__ proof, float* __restrict__ v1){
  __shared__ float red[8][32][32];
  int t = blockIdx.y;
  LinSeg S = {};
  if (t < 16){
    S.X0 = proof + (size_t)t * 32768; S.K1 = 1024; S.W1 = vw1; S.ld1 = 2048; S.b1 = vb1;
    S.Y = proof + (size_t)(t + 1) * 32768; S.K2 = 1024; S.W2 = vw1 + 1024; S.ld2 = 2048;
  } else {
    S.X0 = proof + (size_t)16 * 32768; S.K1 = 1024; S.W1 = verw1; S.ld1 = 1024; S.b1 = verb1;
  }
  S.out = v1 + (size_t)t * 32768; S.N = 1024; S.act = 1;
  lin_body(S, blockIdx.x, threadIdx.x, red);
}

__global__ __launch_bounds__(256) void dotsig_b_k(const float* __restrict__ v1,
    const float* __restrict__ w2v, const float* __restrict__ b2v,
    const float* __restrict__ w2ver, const float* __restrict__ b2ver,
    float* __restrict__ out_vals, float* __restrict__ out_valid){
  int t = blockIdx.x;
  const float* w = (t < 16) ? w2v : w2ver;
  const float* bs = (t < 16) ? b2v : b2ver;
  const float* x = v1 + (size_t)t * 32768;
  int b = threadIdx.x >> 3, l8 = threadIdx.x & 7;
  const float* xr = x + (size_t)b * 1024;
  float acc = 0.f;
  #pragma unroll 8
  for (int kk = 0; kk < 32; kk++){
    int k = kk * 32 + l8 * 4;
    float4 xv = *(const float4*)(xr + k);
    float4 wv = *(const float4*)(w + k);
    acc += xv.x * wv.x + xv.y * wv.y + xv.z * wv.z + xv.w * wv.w;
  }
  acc += __shfl_xor(acc, 1); acc += __shfl_xor(acc, 2); acc += __shfl_xor(acc, 4);
  if (l8 == 0){
    float r = sigm_f(acc + bs[0]);
    if (t < 16) out_vals[t * 32 + b] = r; else out_valid[b] = r;
  }
}

// ---------------- attention + rule softmax/sel + LSTM0 gates, one dispatch ----------------
__global__ __launch_bounds__(256) void attn_rg0_k(const float* __restrict__ q,
    const u16* __restrict__ Kt, const u16* __restrict__ Vb,
    float* __restrict__ afull, float* __restrict__ ctx0,
    const float* __restrict__ h1a, const float* __restrict__ w2, const float* __restrict__ b2,
    const float* __restrict__ emb, float* __restrict__ probs_out, float* __restrict__ sel,
    const float* __restrict__ g, const float* __restrict__ cprev,
    float* __restrict__ cn, float* __restrict__ hn)
{
  int tid = threadIdx.x;
  if (blockIdx.x >= 544){                        // ---- LSTM0 gates (128 blocks)
    int idx = (blockIdx.x - 544) * 256 + tid;
    int b = idx >> 10, j = idx & 1023;
    const float* gr = g + (size_t)b * 4096;
    float gi = gr[j], gf = gr[1024 + j], gg = gr[2048 + j], go = gr[3072 + j];
    float c = sigm_f(gf) * cprev[idx] + sigm_f(gi) * tanhf(gg);
    cn[idx] = c;
    hn[idx] = sigm_f(go) * tanhf(c);
    return;
  }
  if (blockIdx.x >= 512){                        // ---- rule2 softmax + sel (32 blocks)
    int b = blockIdx.x - 512;
    __shared__ float lg[32], pshared[32];
    int j = tid >> 3, l8 = tid & 7;
    const float* xr = h1a + b * 1024;
    const float* wr = w2 + j * 1024;
    float acc = 0.f;
    #pragma unroll 8
    for (int kk = 0; kk < 32; kk++){
      int k = kk * 32 + l8 * 4;
      float4 xv = *(const float4*)(xr + k);
      float4 wv = *(const float4*)(wr + k);
      acc += xv.x * wv.x + xv.y * wv.y + xv.z * wv.z + xv.w * wv.w;
    }
    acc += __shfl_xor(acc, 1); acc += __shfl_xor(acc, 2); acc += __shfl_xor(acc, 4);
    if (l8 == 0) lg[j] = acc + b2[j];
    __syncthreads();
    if (tid < 32){
      float v = lg[tid];
      float m = v;
      for (int o = 1; o < 32; o <<= 1) m = fmaxf(m, __shfl_xor(m, o));
      float e = __expf(v - m);
      float s = e;
      for (int o = 1; o < 32; o <<= 1) s += __shfl_xor(s, o);
      float p = e / s;
      pshared[tid] = p;
      probs_out[b * 32 + tid] = p;
    }
    __syncthreads();
    for (int j2 = tid; j2 < 1024; j2 += 256){
      float a2 = 0.f;
      #pragma unroll
      for (int r = 0; r < 32; r++) a2 += pshared[r] * emb[r * 1024 + j2];
      sel[b * 1024 + j2] = a2;
    }
    return;
  }
  // ---- attention (512 blocks, one per (b,h))
  int bh = blockIdx.x;
  int b = bh >> 4, h = bh & 15;
  __shared__ float qs[64];
  __shared__ float sc[1024];
  __shared__ float rmx[4], rsm[4];
  __shared__ float ctxp[8][64];
  if (tid < 64) qs[tid] = q[bh * 64 + tid];
  __syncthreads();
  const u32* kt = (const u32*)(Kt + (size_t)bh * 65536);   // [d][s/2] pairs
  float a0 = 0.f, a1 = 0.f, a2 = 0.f, a3 = 0.f;
  #pragma unroll 8
  for (int d = 0; d < 64; d++){
    float qd = qs[d];
    u32 p0 = kt[d * 512 + tid];
    u32 p1 = kt[d * 512 + tid + 256];
    a0 += qd * bf2f((u16)(p0 & 0xffff)); a1 += qd * bf2f((u16)(p0 >> 16));
    a2 += qd * bf2f((u16)(p1 & 0xffff)); a3 += qd * bf2f((u16)(p1 >> 16));
  }
  float mx = fmaxf(fmaxf(a0, a1), fmaxf(a2, a3));
  for (int o = 1; o < 64; o <<= 1) mx = fmaxf(mx, __shfl_xor(mx, o));
  if ((tid & 63) == 0) rmx[tid >> 6] = mx;
  __syncthreads();
  mx = fmaxf(fmaxf(rmx[0], rmx[1]), fmaxf(rmx[2], rmx[3]));
  float e0 = __expf(a0 - mx), e1 = __expf(a1 - mx), e2 = __expf(a2 - mx), e3 = __expf(a3 - mx);
  float sm = e0 + e1 + e2 + e3;
  for (int o = 1; o < 64; o <<= 1) sm += __shfl_xor(sm, o);
  if ((tid & 63) == 0) rsm[tid >> 6] = sm;
  __syncthreads();
  sm = rsm[0] + rsm[1] + rsm[2] + rsm[3];
  float inv = 1.f / sm;
  float* ar = afull + (size_t)bh * 1024;
  float2 w0 = make_float2(e0 * inv, e1 * inv);
  float2 w1 = make_float2(e2 * inv, e3 * inv);
  *(float2*)(sc + 2 * tid) = w0;       *(float2*)(ar + 2 * tid) = w0;
  *(float2*)(sc + 512 + 2 * tid) = w1; *(float2*)(ar + 512 + 2 * tid) = w1;
  __syncthreads();
  int d2 = (tid & 31) * 2, chunk = tid >> 5;        // 8 chunks of 128 s
  const u16* vb = Vb + ((size_t)(b * 1024) * 16 + h) * 64 + d2;
  float c0 = 0.f, c1 = 0.f;
  for (int s = chunk * 128; s < chunk * 128 + 128; s++){
    u32 vv = *(const u32*)(vb + (size_t)s * 1024);
    float wv = sc[s];
    c0 += wv * bf2f((u16)(vv & 0xffff));
    c1 += wv * bf2f((u16)(vv >> 16));
  }
  *(float2*)&ctxp[chunk][d2] = make_float2(c0, c1);
  __syncthreads();
  if (tid < 64){
    float r = 0.f;
    #pragma unroll
    for (int c = 0; c < 8; c++) r += ctxp[c][tid];
    ctx0[bh * 64 + tid] = r;
  }
}

// ---------------- LSTM1 gates + zero LN row-stats ----------------
__global__ __launch_bounds__(256) void gz_k(const float* __restrict__ g, const float* __restrict__ cprev,
                                            float* __restrict__ cn, float* __restrict__ hn,
                                            float* __restrict__ stats){
  if (blockIdx.x == 0 && threadIdx.x < 64) stats[threadIdx.x] = 0.f;
  int idx = blockIdx.x * 256 + threadIdx.x;     // 32768
  int b = idx >> 10, j = idx & 1023;
  const float* gr = g + (size_t)b * 4096;
  float gi = gr[j], gf = gr[1024 + j], gg = gr[2048 + j], go = gr[3072 + j];
  float c = sigm_f(gf) * cprev[idx] + sigm_f(gi) * tanhf(gg);
  cn[idx] = c;
  hn[idx] = sigm_f(go) * tanhf(c);
}

// ---------------- batched attn head-mean over all 16 steps ----------------
__global__ __launch_bounds__(256) void attnavg_all_k(const float* __restrict__ afull, float* __restrict__ out){
  int idx = blockIdx.x * 256 + threadIdx.x;     // 16*32768
  int t = idx >> 15, r = idx & 32767;
  int b = r >> 10, s = r & 1023;
  const float* base = afull + (size_t)t * 524288 + (size_t)b * 16384;
  float acc = 0.f;
  #pragma unroll
  for (int h = 0; h < 16; h++) acc += base[h * 1024 + s];
  out[idx] = acc * (1.f / 16.f);
}

extern "C" void kernel_launch(void* const* d_in, const int* in_sizes, int n_in,
                              void* d_out, int out_size, void* d_ws, size_t ws_size,
                              hipStream_t stream) {
  const float* comp      = (const float*)d_in[0];
  const float* rule_w1   = (const float*)d_in[2];
  const float* rule_b1   = (const float*)d_in[3];
  const float* rule_w2   = (const float*)d_in[4];
  const float* rule_b2   = (const float*)d_in[5];
  const float* rule_emb  = (const float*)d_in[6];
  const float* attn_in_w = (const float*)d_in[7];
  const float* attn_in_b = (const float*)d_in[8];
  const float* attn_out_w= (const float*)d_in[9];
  const float* attn_out_b= (const float*)d_in[10];
  const float* wih0 = (const float*)d_in[11];
  const float* whh0 = (const float*)d_in[12];
  const float* bih0 = (const float*)d_in[13];
  const float* bhh0 = (const float*)d_in[14];
  const float* wih1 = (const float*)d_in[15];
  const float* whh1 = (const float*)d_in[16];
  const float* bih1 = (const float*)d_in[17];
  const float* bhh1 = (const float*)d_in[18];
  const float* gen_w1 = (const float*)d_in[19];
  const float* gen_b1 = (const float*)d_in[20];
  const float* ln_g   = (const float*)d_in[21];
  const float* ln_b   = (const float*)d_in[22];
  const float* gen_w2 = (const float*)d_in[23];
  const float* gen_b2 = (const float*)d_in[24];
  const float* val_w1 = (const float*)d_in[25];
  const float* val_b1 = (const float*)d_in[26];
  const float* val_w2 = (const float*)d_in[27];
  const float* val_b2 = (const float*)d_in[28];
  const float* ver_w1 = (const float*)d_in[29];
  const float* ver_b1 = (const float*)d_in[30];
  const float* ver_w2 = (const float*)d_in[31];
  const float* ver_b2 = (const float*)d_in[32];

  float* out_f     = (float*)d_out;
  float* out_proof = out_f;                       // (17,32,1024)
  float* out_valid = out_f + 17 * 32768;          // (32,1)
  float* out_probs = out_valid + 32;              // (16,32,32)
  float* out_vals  = out_probs + 16 * 1024;       // (16,32,1)
  float* out_attn  = out_vals + 16 * 32;          // (16,32,1024)

  char* wp = (char*)d_ws;
  auto carve = [&](size_t bytes) -> void* {
    void* p = (void*)wp; wp += (bytes + 255) & ~(size_t)255; return p;
  };
  u16* Kt    = (u16*)carve((size_t)33554432 * 2);   // [b][hd][s]
  u16* Vb    = (u16*)carve((size_t)33554432 * 2);   // [b][s][hd]
  u16* compb = (u16*)carve((size_t)33554432 * 2);   // bf16 comp; afull_all aliases after gemms
  float* afull_all = (float*)compb;                 // 16 * 512 * 1024 fp32 = 32MB (<= 64MB)
  u16* rw1b  = (u16*)carve(2097152);
  u16* wqb   = (u16*)carve(2097152);
  u16* wkb   = (u16*)carve(2097152);
  u16* wvb   = (u16*)carve(2097152);
  u16* aowb  = (u16*)carve(2097152);
  u16* wih0b = (u16*)carve(8388608);
  u16* whh0b = (u16*)carve(8388608);
  u16* wih1b = (u16*)carve(8388608);
  u16* whh1b = (u16*)carve(8388608);
  u16* gw1b  = (u16*)carve(4194304);
  u16* gw2b  = (u16*)carve(4194304);
  u16* vw1b  = (u16*)carve(4194304);
  u16* verw1b= (u16*)carve(2097152);
  float* psb[2]  = { (float*)carve(131072), (float*)carve(131072) };
  float* h0b[2]  = { (float*)carve(131072), (float*)carve(131072) };
  float* c0b[2]  = { (float*)carve(131072), (float*)carve(131072) };
  float* h1b[2]  = { (float*)carve(131072), (float*)carve(131072) };
  float* c1b[2]  = { (float*)carve(131072), (float*)carve(131072) };
  float* h1act = (float*)carve(131072);
  float* sel   = (float*)carve(131072);
  float* qbuf  = (float*)carve(131072);
  float* ctx0  = (float*)carve(131072);
  float* ctxb  = (float*)carve(131072);
  float* gbuf  = (float*)carve(524288);
  float* zbuf  = (float*)carve(262144);
  float* v1buf = (float*)carve(2228224);            // 17 * 32768 fp32
  float* lnstats = (float*)carve(256);              // rowsum[32] + rowsumsq[32]
  (void)ws_size; (void)in_sizes; (void)n_in; (void)out_size;

  // ---- weight casts (one launch) + comp cast ----
  CastJobs J;
  const float* srcs[13] = { rule_w1, attn_in_w, attn_in_w + 1048576, attn_in_w + 2097152,
                            attn_out_w, wih0, whh0, wih1, whh1, gen_w1, gen_w2, val_w1, ver_w1 };
  u16* dsts[13] = { rw1b, wqb, wkb, wvb, aowb, wih0b, whh0b, wih1b, whh1b, gw1b, gw2b, vw1b, verw1b };
  int sizes[13] = { 1048576, 1048576, 1048576, 1048576, 1048576,
                    4194304, 4194304, 4194304, 4194304, 2097152, 2097152, 2097152, 1048576 };
  int st = 0;
  for (int i = 0; i < 13; i++){ J.s[i] = srcs[i]; J.d[i] = dsts[i]; J.start[i] = st; st += sizes[i] / 1024; }
  J.start[13] = st;
  cast_all_k<<<dim3(st), dim3(256), 0, stream>>>(J);
  cast_k<<<dim3(32768), dim3(256), 0, stream>>>(comp, compb, 33554432);

  gemmkv_k<<<dim3(256, 8, 2), dim3(256), 0, stream>>>(compb, wkb, wvb,
      attn_in_b + 1024, attn_in_b + 2048, Kt, Vb);

  init_k<<<dim3(128), dim3(256), 0, stream>>>(comp, psb[0], out_proof,
      h0b[0], c0b[0], h1b[0], c1b[0]);

  auto mkseg = [&](const float* X0, const float* Xa, const float* Xb, const float* Xc,
                   int K1, const u16* W1, int ld1, const float* bb1,
                   const float* Y, int K2, const u16* W2, int ld2, const float* bb2,
                   float* out, int N, int act, float scl, float* out2) -> LinSeg {
    LinSeg S = {};
    S.X0 = X0; S.Xa = Xa; S.Xb = Xb; S.Xc = Xc; S.K1 = K1; S.W1 = W1; S.ld1 = ld1; S.b1 = bb1;
    S.Y = Y; S.K2 = K2; S.W2 = W2; S.ld2 = ld2; S.b2 = bb2;
    S.out = out; S.N = N; S.act = act; S.scale = scl; S.out2 = out2;
    return S;
  };
  auto lin1 = [&](LinSeg S){
    linmulti_k<<<dim3(S.N / 32), dim3(512), 0, stream>>>(S, S, S, S.N / 32, 0);
  };

  for (int t = 0; t < 16; t++){
    int cur = t & 1, nx = cur ^ 1;
    float* ps = psb[cur];
    float* afull_t = afull_all + (size_t)t * 524288;
    // D1: rule h1 (gelu), q (scaled), lstm0 gates GEMM
    LinSeg sRule = mkseg(ps, 0, 0, 0, 1024, rw1b, 1024, rule_b1, 0, 0, 0, 0, 0, h1act, 1024, 1, 0.f, 0);
    LinSeg sQ    = mkseg(ps, 0, 0, 0, 1024, wqb, 1024, attn_in_b, 0, 0, 0, 0, 0, qbuf, 1024, 2, 0.125f, 0);
    LinSeg sL0   = mkseg(ps, 0, 0, 0, 1024, wih0b, 1024, bih0, h0b[cur], 1024, whh0b, 1024, bhh0,
                         gbuf, 4096, 0, 0.f, 0);
    linmulti_k<<<dim3(192), dim3(512), 0, stream>>>(sRule, sQ, sL0, 32, 32);
    // D2: attention + rule2 softmax/sel + lstm0 gates
    attn_rg0_k<<<dim3(672), dim3(256), 0, stream>>>(qbuf, Kt, Vb, afull_t, ctx0,
        h1act, rule_w2, rule_b2, rule_emb, out_probs + t * 1024, sel,
        gbuf, c0b[cur], c0b[nx], h0b[nx]);
    // D3: ctx proj + lstm1 gates GEMM
    LinSeg sCtx = mkseg(ctx0, 0, 0, 0, 1024, aowb, 1024, attn_out_b, 0, 0, 0, 0, 0, ctxb, 1024, 0, 0.f, 0);
    LinSeg sL1  = mkseg(h0b[nx], 0, 0, 0, 1024, wih1b, 1024, bih1, h1b[cur], 1024, whh1b, 1024, bhh1,
                        gbuf, 4096, 0, 0.f, 0);
    linmulti_k<<<dim3(160), dim3(512), 0, stream>>>(sCtx, sL1, sL1, 32, 128);
    // D4: lstm1 gates + zero LN stats
    gz_k<<<dim3(128), dim3(256), 0, stream>>>(gbuf, c1b[cur], c1b[nx], h1b[nx], lnstats);
    // D5: z = (ps+sel+ctx+mem) @ gw1^T + b, epilogue accumulates LN row stats
    LinSeg sG1 = mkseg(ps, sel, ctxb, h1b[nx], 1024, gw1b, 1024, gen_b1, 0, 0, 0, 0, 0,
                       zbuf, 2048, 0, 0.f, 0);
    sG1.stats = lnstats;
    lin1(sG1);
    // D6: nxt = gelu(LN(z)) @ gw2^T + b   (LN+gelu applied on A-load)
    LinSeg sG2 = mkseg(zbuf, 0, 0, 0, 2048, gw2b, 2048, gen_b2, 0, 0, 0, 0, 0,
                       psb[nx], 1024, 0, 0.f, out_proof + (size_t)(t + 1) * 32768);
    sG2.lng = ln_g; sG2.lnb = ln_b; sG2.lnstats = lnstats;
    lin1(sG2);
  }
  // post-loop: batched value heads (16) + verifier (grid.y = 17)
  valver_k<<<dim3(32, 17), dim3(512), 0, stream>>>(vw1b, val_b1, verw1b, ver_b1, out_proof, v1buf);
  dotsig_b_k<<<dim3(17), dim3(256), 0, stream>>>(v1buf, val_w2, val_b2, ver_w2, ver_b2,
      out_vals, out_valid);
  // batched attn head-mean
  attnavg_all_k<<<dim3(2048), dim3(256), 0, stream>>>(afull_all, out_attn);
}

// Round 4
// 1925.376 us; speedup vs baseline: 1.3281x; 1.0120x over previous
//
#include <hip/hip_runtime.h>

typedef unsigned short u16;
typedef unsigned int u32;
typedef __attribute__((ext_vector_type(8))) short short8v;   // 8 bf16 (4 VGPRs)
typedef __attribute__((ext_vector_type(4))) float f32x4;

#define MFMA16(a,b,c) __builtin_amdgcn_mfma_f32_16x16x32_bf16((a),(b),(c),0,0,0)

__device__ __forceinline__ u16 f2bf(float f){
  u32 u = __float_as_uint(f);
  return (u16)((u + 0x7fffu + ((u >> 16) & 1u)) >> 16);   // RNE
}
__device__ __forceinline__ float bf2f(u16 h){ return __uint_as_float(((u32)h) << 16); }
__device__ __forceinline__ float gelu_f(float x){ return 0.5f * x * (1.f + erff(x * 0.70710678118654752f)); }
__device__ __forceinline__ float sigm_f(float x){ return 1.f / (1.f + __expf(-x)); }
__device__ __forceinline__ void acc4(float4& a, const float4 b){ a.x+=b.x; a.y+=b.y; a.z+=b.z; a.w+=b.w; }

// async global->LDS, 16B per lane (HW: wave-uniform LDS base + lane*16)
__device__ __forceinline__ void gl16(const void* g, void* l){
  __builtin_amdgcn_global_load_lds((const __attribute__((address_space(1))) u32*)g,
                                   (__attribute__((address_space(3))) u32*)l, 16, 0, 0);
}

// ---------------- fused weight cast fp32 -> bf16 (13 jobs, one launch) ----------------
struct CastJobs { const float* s[13]; u16* d[13]; int start[14]; };
__global__ __launch_bounds__(256) void cast_all_k(CastJobs J){
  int bx = blockIdx.x, j = 0;
  #pragma unroll
  for (int t = 0; t < 13; t++) if (bx >= J.start[t + 1]) j = t + 1;
  int i = (bx - J.start[j]) * 1024 + threadIdx.x * 4;
  float4 v = *(const float4*)(J.s[j] + i);
  ushort4 o; o.x = f2bf(v.x); o.y = f2bf(v.y); o.z = f2bf(v.z); o.w = f2bf(v.w);
  *(ushort4*)(J.d[j] + i) = o;
}

__global__ __launch_bounds__(256) void cast_k(const float* __restrict__ s, u16* __restrict__ d, int n){
  int i = (blockIdx.x * 256 + threadIdx.x) * 4;
  if (i + 3 < n){
    float4 v = *(const float4*)(s + i);
    ushort4 o; o.x = f2bf(v.x); o.y = f2bf(v.y); o.z = f2bf(v.z); o.w = f2bf(v.w);
    *(ushort4*)(d + i) = o;
  }
}

// ---------------- init ----------------
__global__ __launch_bounds__(256) void init_k(const float* __restrict__ comp, float* ps0, float* outp,
                                              float* h0, float* c0, float* h1, float* c1){
  int i = blockIdx.x * 256 + threadIdx.x;       // 32768
  int b = i >> 10, hh = i & 1023;
  float v = comp[(size_t)b * 1048576 + hh];
  ps0[i] = v; outp[i] = v;
  h0[i] = 0.f; c0[i] = 0.f; h1[i] = 0.f; c1[i] = 0.f;
}

// ---------------- fused K/V GEMM: BK=64, XOR-swizzled staging, XCD-chunked grid ----------------
// z=0: V[bs][hd] = compb @ Wv^T + bv
// z=1: Kt[b][hd][s] = Wk @ compb^T + bk
__global__ __launch_bounds__(256) void gemmkv_k(const u16* __restrict__ compb,
    const u16* __restrict__ Wk, const u16* __restrict__ Wv,
    const float* __restrict__ bk, const float* __restrict__ bv,
    u16* __restrict__ Kt, u16* __restrict__ Vb)
{
  __shared__ u16 As[128 * 64];
  __shared__ u16 Bs[128 * 64];
  int tid = threadIdx.x;
  // XCD-chunked: each XCD owns 32 consecutive comp panels; weight panel varies fastest.
  int x = blockIdx.x;                 // 0..2047
  int xcd = x & 7, p = x >> 3;        // p: 0..255
  int cpanel = xcd * 32 + (p >> 3);   // comp panel 0..255 (reused by 8 consecutive same-XCD blocks)
  int wpanel = p & 7;                 // weight panel 0..7
  int isK = (blockIdx.z != 0);
  const u16 *msrc, *nsrc; int m0, n0;
  if (!isK){ m0 = cpanel * 128; n0 = wpanel * 128; msrc = compb; nsrc = Wv; }
  else     { m0 = wpanel * 128; n0 = cpanel * 128; msrc = Wk;    nsrc = compb; }

  int w = tid >> 6, l = tid & 63, lr = l & 15, lk = l >> 4;
  int wm = (w >> 1) * 64, wn = (w & 1) * 64;
  f32x4 acc[4][4];
  #pragma unroll
  for (int i = 0; i < 4; i++)
    #pragma unroll
    for (int j = 0; j < 4; j++) acc[i][j] = (f32x4){0.f,0.f,0.f,0.f};

  for (int kc = 0; kc < 1024; kc += 64){
    // stage 128x64 u16 per matrix; linear LDS dest, inverse-swizzled global source (rule #21)
    #pragma unroll
    for (int r = 0; r < 4; r++){
      int s = tid + r * 256;                 // 16B-chunk index 0..1023
      int row = s >> 3, pp = s & 7;
      int lg = pp ^ (row & 7);               // logical k-slot stored at phys slot pp
      gl16(msrc + (size_t)(m0 + row) * 1024 + kc + lg * 8, As + s * 8);
      gl16(nsrc + (size_t)(n0 + row) * 1024 + kc + lg * 8, Bs + s * 8);
    }
    __syncthreads();
    #pragma unroll
    for (int kk = 0; kk < 2; kk++){
      short8v a[4], bb[4];
      #pragma unroll
      for (int mi = 0; mi < 4; mi++){
        int row = wm + mi * 16 + lr;
        int ph = (kk * 4 + lk) ^ (row & 7);
        a[mi] = *(const short8v*)(As + row * 64 + ph * 8);
      }
      #pragma unroll
      for (int ni = 0; ni < 4; ni++){
        int row = wn + ni * 16 + lr;
        int ph = (kk * 4 + lk) ^ (row & 7);
        bb[ni] = *(const short8v*)(Bs + row * 64 + ph * 8);
      }
      #pragma unroll
      for (int mi = 0; mi < 4; mi++)
        #pragma unroll
        for (int ni = 0; ni < 4; ni++)
          acc[mi][ni] = MFMA16(a[mi], bb[ni], acc[mi][ni]);
    }
    __syncthreads();
  }
  #pragma unroll
  for (int mi = 0; mi < 4; mi++)
    #pragma unroll
    for (int ni = 0; ni < 4; ni++)
      #pragma unroll
      for (int r = 0; r < 4; r++){
        int row = m0 + wm + mi * 16 + lk * 4 + r;
        int col = n0 + wn + ni * 16 + lr;
        if (!isK){
          Vb[(size_t)row * 1024 + col] = f2bf(acc[mi][ni][r] + bv[col]);
        } else {
          int b = col >> 10, s = col & 1023;
          Kt[((size_t)b * 1024 + row) * 1024 + s] = f2bf(acc[mi][ni][r] + bk[row]);
        }
      }
}

// ---------------- multi-segment M=32 MFMA linear (opt: fused LSTM gates / LN) ----------------
struct LinSeg {
  const float* X0; const float* Xa; const float* Xb; const float* Xc;  // summed A inputs
  const u16* W1; const float* b1;
  const float* Y; const u16* W2; const float* b2;                     // optional 2nd GEMM
  float* out; float* out2;
  int K1, ld1, K2, ld2, N, act, gate;   // act: 0 none, 1 gelu, 2 scale; gate: LSTM epilogue
  float scale;
  float* stats;                   // if set: epilogue accumulates row sum/sumsq (atomics)
  const float* lng; const float* lnb; const float* lnstats;  // if lng: LN+gelu on A-load
  const float* cprev; float* cout; float* hout;              // gate mode
};

__device__ __forceinline__ short8v pack8(float4 v0, float4 v1){
  short8v r;
  r[0]=(short)f2bf(v0.x); r[1]=(short)f2bf(v0.y); r[2]=(short)f2bf(v0.z); r[3]=(short)f2bf(v0.w);
  r[4]=(short)f2bf(v1.x); r[5]=(short)f2bf(v1.y); r[6]=(short)f2bf(v1.z); r[7]=(short)f2bf(v1.w);
  return r;
}

__device__ __forceinline__ short8v load_sum8(const LinSeg& S, int row, int kb){
  size_t o = (size_t)row * S.K1 + kb;
  float4 v0 = *(const float4*)(S.X0 + o);
  float4 v1 = *(const float4*)(S.X0 + o + 4);
  if (S.lng){
    float mu = S.lnstats[row] * (1.f / 2048.f);
    float ms = S.lnstats[32 + row] * (1.f / 2048.f);
    float rstd = rsqrtf(ms - mu * mu + 1e-5f);
    float4 g0 = *(const float4*)(S.lng + kb), g1 = *(const float4*)(S.lng + kb + 4);
    float4 b0 = *(const float4*)(S.lnb + kb), b1 = *(const float4*)(S.lnb + kb + 4);
    v0.x = gelu_f((v0.x - mu) * rstd * g0.x + b0.x);
    v0.y = gelu_f((v0.y - mu) * rstd * g0.y + b0.y);
    v0.z = gelu_f((v0.z - mu) * rstd * g0.z + b0.z);
    v0.w = gelu_f((v0.w - mu) * rstd * g0.w + b0.w);
    v1.x = gelu_f((v1.x - mu) * rstd * g1.x + b1.x);
    v1.y = gelu_f((v1.y - mu) * rstd * g1.y + b1.y);
    v1.z = gelu_f((v1.z - mu) * rstd * g1.z + b1.z);
    v1.w = gelu_f((v1.w - mu) * rstd * g1.w + b1.w);
  } else {
    if (S.Xa){ acc4(v0, *(const float4*)(S.Xa + o)); acc4(v1, *(const float4*)(S.Xa + o + 4)); }
    if (S.Xb){ acc4(v0, *(const float4*)(S.Xb + o)); acc4(v1, *(const float4*)(S.Xb + o + 4)); }
    if (S.Xc){ acc4(v0, *(const float4*)(S.Xc + o)); acc4(v1, *(const float4*)(S.Xc + o + 4)); }
  }
  return pack8(v0, v1);
}
__device__ __forceinline__ short8v load_y8(const float* __restrict__ p){
  return pack8(*(const float4*)(p), *(const float4*)(p + 4));
}

typedef float Red32[32][32];

__device__ void lin_body(const LinSeg& S, int bi, int tid, Red32* red){
  int c0 = bi * 32, j0 = bi * 8;
  int w = tid >> 6, l = tid & 63, lr = l & 15, lk = l >> 4;
  // gate mode: local col c -> weight row (c>>3)*1024 + j0 + (c&7)
  int wc0 = S.gate ? ((lr >> 3) << 10) + j0 + (lr & 7) : c0 + lr;
  int wc1 = S.gate ? (((lr + 16) >> 3) << 10) + j0 + ((lr + 16) & 7) : c0 + lr + 16;
  f32x4 acc[2][2];
  #pragma unroll
  for (int i = 0; i < 2; i++)
    #pragma unroll
    for (int j = 0; j < 2; j++) acc[i][j] = (f32x4){0.f,0.f,0.f,0.f};

  {
    int chunk = S.K1 >> 3;
    int kb0 = w * chunk + lk * 8;
    for (int kk = 0; kk < chunk; kk += 32){
      int kb = kb0 + kk;
      short8v a0 = load_sum8(S, lr, kb);
      short8v a1 = load_sum8(S, lr + 16, kb);
      short8v w0 = *(const short8v*)(S.W1 + (size_t)wc0 * S.ld1 + kb);
      short8v w1 = *(const short8v*)(S.W1 + (size_t)wc1 * S.ld1 + kb);
      acc[0][0] = MFMA16(a0, w0, acc[0][0]);
      acc[0][1] = MFMA16(a0, w1, acc[0][1]);
      acc[1][0] = MFMA16(a1, w0, acc[1][0]);
      acc[1][1] = MFMA16(a1, w1, acc[1][1]);
    }
  }
  if (S.Y){
    int chunk = S.K2 >> 3;
    int kb0 = w * chunk + lk * 8;
    for (int kk = 0; kk < chunk; kk += 32){
      int kb = kb0 + kk;
      short8v a0 = load_y8(S.Y + (size_t)lr * S.K2 + kb);
      short8v a1 = load_y8(S.Y + (size_t)(lr + 16) * S.K2 + kb);
      short8v w0 = *(const short8v*)(S.W2 + (size_t)wc0 * S.ld2 + kb);
      short8v w1 = *(const short8v*)(S.W2 + (size_t)wc1 * S.ld2 + kb);
      acc[0][0] = MFMA16(a0, w0, acc[0][0]);
      acc[0][1] = MFMA16(a0, w1, acc[0][1]);
      acc[1][0] = MFMA16(a1, w0, acc[1][0]);
      acc[1][1] = MFMA16(a1, w1, acc[1][1]);
    }
  }
  #pragma unroll
  for (int mi = 0; mi < 2; mi++)
    #pragma unroll
    for (int ni = 0; ni < 2; ni++)
      #pragma unroll
      for (int r = 0; r < 4; r++)
        red[w][mi * 16 + lk * 4 + r][ni * 16 + lr] = acc[mi][ni][r];
  __syncthreads();
  if (S.gate){
    if (tid < 256){
      int row = tid >> 3, j = tid & 7;
      float s[4];
      #pragma unroll
      for (int g = 0; g < 4; g++){
        float v = 0.f;
        #pragma unroll
        for (int ww = 0; ww < 8; ww++) v += red[ww][row][g * 8 + j];
        s[g] = v;
      }
      int gc = j0 + j;
      float gI = s[0] + S.b1[gc]        + S.b2[gc];
      float gF = s[1] + S.b1[1024 + gc] + S.b2[1024 + gc];
      float gG = s[2] + S.b1[2048 + gc] + S.b2[2048 + gc];
      float gO = s[3] + S.b1[3072 + gc] + S.b2[3072 + gc];
      int idx = row * 1024 + gc;
      float cN = sigm_f(gF) * S.cprev[idx] + sigm_f(gI) * tanhf(gG);
      S.cout[idx] = cN;
      S.hout[idx] = sigm_f(gO) * tanhf(cN);
    }
    return;
  }
  float vout[2]; int iout[2];
  int cnt = 0;
  for (int i = tid; i < 1024; i += 512){
    int row = i >> 5, col = i & 31;
    float v = 0.f;
    #pragma unroll
    for (int ww = 0; ww < 8; ww++) v += red[ww][row][col];
    v += S.b1[c0 + col];
    if (S.b2) v += S.b2[c0 + col];
    if (S.act == 1) v = gelu_f(v);
    else if (S.act == 2) v *= S.scale;
    S.out[(size_t)row * S.N + c0 + col] = v;
    if (S.out2) S.out2[(size_t)row * S.N + c0 + col] = v;
    vout[cnt] = v; iout[cnt] = i; cnt++;
  }
  if (S.stats){
    __syncthreads();
    float* rf = (float*)red;
    rf[iout[0]] = vout[0]; rf[1024 + iout[0]] = vout[0] * vout[0];
    rf[iout[1]] = vout[1]; rf[1024 + iout[1]] = vout[1] * vout[1];
    __syncthreads();
    if (tid < 32){
      float s = 0.f, s2 = 0.f;
      #pragma unroll
      for (int cc = 0; cc < 32; cc++){ s += rf[tid * 32 + cc]; s2 += rf[1024 + tid * 32 + cc]; }
      atomicAdd(S.stats + tid, s);
      atomicAdd(S.stats + 32 + tid, s2);
    }
  }
}

__global__ __launch_bounds__(512) void linmulti_k(LinSeg s0, LinSeg s1, LinSeg s2, int n0, int n1,
                                                  float* zero64){
  __shared__ float red[8][32][32];
  int bx = blockIdx.x, tid = threadIdx.x;
  if (zero64 && bx == 0 && tid < 64) zero64[tid] = 0.f;
  if (bx < n0) lin_body(s0, bx, tid, red);
  else if (bx < n0 + n1) lin_body(s1, bx - n0, tid, red);
  else lin_body(s2, bx - n0 - n1, tid, red);
}

// ---------------- batched value head (16 steps) + verifier, grid (32, 17) ----------------
__global__ __launch_bounds__(512) void valver_k(const u16* __restrict__ vw1, const float* __restrict__ vb1,
    const u16* __restrict__ verw1, const float* __restrict__ verb1,
    const float* __restrict__ proof, float* __restrict__ v1){
  __shared__ float red[8][32][32];
  int t = blockIdx.y;
  LinSeg S = {};
  if (t < 16){
    S.X0 = proof + (size_t)t * 32768; S.K1 = 1024; S.W1 = vw1; S.ld1 = 2048; S.b1 = vb1;
    S.Y = proof + (size_t)(t + 1) * 32768; S.K2 = 1024; S.W2 = vw1 + 1024; S.ld2 = 2048;
  } else {
    S.X0 = proof + (size_t)16 * 32768; S.K1 = 1024; S.W1 = verw1; S.ld1 = 1024; S.b1 = verb1;
  }
  S.out = v1 + (size_t)t * 32768; S.N = 1024; S.act = 1;
  lin_body(S, blockIdx.x, threadIdx.x, red);
}

__global__ __launch_bounds__(256) void dotsig_b_k(const float* __restrict__ v1,
    const float* __restrict__ w2v, const float* __restrict__ b2v,
    const float* __restrict__ w2ver, const float* __restrict__ b2ver,
    float* __restrict__ out_vals, float* __restrict__ out_valid){
  int t = blockIdx.x;
  const float* w = (t < 16) ? w2v : w2ver;
  const float* bs = (t < 16) ? b2v : b2ver;
  const float* x = v1 + (size_t)t * 32768;
  int b = threadIdx.x >> 3, l8 = threadIdx.x & 7;
  const float* xr = x + (size_t)b * 1024;
  float acc = 0.f;
  #pragma unroll 8
  for (int kk = 0; kk < 32; kk++){
    int k = kk * 32 + l8 * 4;
    float4 xv = *(const float4*)(xr + k);
    float4 wv = *(const float4*)(w + k);
    acc += xv.x * wv.x + xv.y * wv.y + xv.z * wv.z + xv.w * wv.w;
  }
  acc += __shfl_xor(acc, 1); acc += __shfl_xor(acc, 2); acc += __shfl_xor(acc, 4);
  if (l8 == 0){
    float r = sigm_f(acc + bs[0]);
    if (t < 16) out_vals[t * 32 + b] = r; else out_valid[b] = r;
  }
}

// ---------------- attention + rule softmax/sel, one dispatch (544 blocks) ----------------
__global__ __launch_bounds__(256) void attn_r2_k(const float* __restrict__ q,
    const u16* __restrict__ Kt, const u16* __restrict__ Vb,
    float* __restrict__ afull, float* __restrict__ ctx0,
    const float* __restrict__ h1a, const float* __restrict__ w2, const float* __restrict__ b2,
    const float* __restrict__ emb, float* __restrict__ probs_out, float* __restrict__ sel)
{
  int tid = threadIdx.x;
  if (blockIdx.x >= 512){                        // ---- rule2 softmax + sel (32 blocks)
    int b = blockIdx.x - 512;
    __shared__ float lg[32], pshared[32];
    int j = tid >> 3, l8 = tid & 7;
    const float* xr = h1a + b * 1024;
    const float* wr = w2 + j * 1024;
    float acc = 0.f;
    #pragma unroll 8
    for (int kk = 0; kk < 32; kk++){
      int k = kk * 32 + l8 * 4;
      float4 xv = *(const float4*)(xr + k);
      float4 wv = *(const float4*)(wr + k);
      acc += xv.x * wv.x + xv.y * wv.y + xv.z * wv.z + xv.w * wv.w;
    }
    acc += __shfl_xor(acc, 1); acc += __shfl_xor(acc, 2); acc += __shfl_xor(acc, 4);
    if (l8 == 0) lg[j] = acc + b2[j];
    __syncthreads();
    if (tid < 32){
      float v = lg[tid];
      float m = v;
      for (int o = 1; o < 32; o <<= 1) m = fmaxf(m, __shfl_xor(m, o));
      float e = __expf(v - m);
      float s = e;
      for (int o = 1; o < 32; o <<= 1) s += __shfl_xor(s, o);
      float p = e / s;
      pshared[tid] = p;
      probs_out[b * 32 + tid] = p;
    }
    __syncthreads();
    for (int j2 = tid; j2 < 1024; j2 += 256){
      float a2 = 0.f;
      #pragma unroll
      for (int r = 0; r < 32; r++) a2 += pshared[r] * emb[r * 1024 + j2];
      sel[b * 1024 + j2] = a2;
    }
    return;
  }
  // ---- attention (512 blocks, one per (b,h))
  int bh = blockIdx.x;
  int b = bh >> 4, h = bh & 15;
  __shared__ float qs[64];
  __shared__ float sc[1024];
  __shared__ float rmx[4], rsm[4];
  __shared__ float ctxp[8][64];
  if (tid < 64) qs[tid] = q[bh * 64 + tid];
  __syncthreads();
  const u32* kt = (const u32*)(Kt + (size_t)bh * 65536);   // [d][s/2] pairs
  float a0 = 0.f, a1 = 0.f, a2 = 0.f, a3 = 0.f;
  #pragma unroll 8
  for (int d = 0; d < 64; d++){
    float qd = qs[d];
    u32 p0 = kt[d * 512 + tid];
    u32 p1 = kt[d * 512 + tid + 256];
    a0 += qd * bf2f((u16)(p0 & 0xffff)); a1 += qd * bf2f((u16)(p0 >> 16));
    a2 += qd * bf2f((u16)(p1 & 0xffff)); a3 += qd * bf2f((u16)(p1 >> 16));
  }
  float mx = fmaxf(fmaxf(a0, a1), fmaxf(a2, a3));
  for (int o = 1; o < 64; o <<= 1) mx = fmaxf(mx, __shfl_xor(mx, o));
  if ((tid & 63) == 0) rmx[tid >> 6] = mx;
  __syncthreads();
  mx = fmaxf(fmaxf(rmx[0], rmx[1]), fmaxf(rmx[2], rmx[3]));
  float e0 = __expf(a0 - mx), e1 = __expf(a1 - mx), e2 = __expf(a2 - mx), e3 = __expf(a3 - mx);
  float sm = e0 + e1 + e2 + e3;
  for (int o = 1; o < 64; o <<= 1) sm += __shfl_xor(sm, o);
  if ((tid & 63) == 0) rsm[tid >> 6] = sm;
  __syncthreads();
  sm = rsm[0] + rsm[1] + rsm[2] + rsm[3];
  float inv = 1.f / sm;
  float* ar = afull + (size_t)bh * 1024;
  float2 w0 = make_float2(e0 * inv, e1 * inv);
  float2 w1 = make_float2(e2 * inv, e3 * inv);
  *(float2*)(sc + 2 * tid) = w0;       *(float2*)(ar + 2 * tid) = w0;
  *(float2*)(sc + 512 + 2 * tid) = w1; *(float2*)(ar + 512 + 2 * tid) = w1;
  __syncthreads();
  int d2 = (tid & 31) * 2, chunk = tid >> 5;        // 8 chunks of 128 s
  const u16* vb = Vb + ((size_t)(b * 1024) * 16 + h) * 64 + d2;
  float c0 = 0.f, c1 = 0.f;
  for (int s = chunk * 128; s < chunk * 128 + 128; s++){
    u32 vv = *(const u32*)(vb + (size_t)s * 1024);
    float wv = sc[s];
    c0 += wv * bf2f((u16)(vv & 0xffff));
    c1 += wv * bf2f((u16)(vv >> 16));
  }
  *(float2*)&ctxp[chunk][d2] = make_float2(c0, c1);
  __syncthreads();
  if (tid < 64){
    float r = 0.f;
    #pragma unroll
    for (int c = 0; c < 8; c++) r += ctxp[c][tid];
    ctx0[bh * 64 + tid] = r;
  }
}

// ---------------- batched attn head-mean over all 16 steps ----------------
__global__ __launch_bounds__(256) void attnavg_all_k(const float* __restrict__ afull, float* __restrict__ out){
  int idx = blockIdx.x * 256 + threadIdx.x;     // 16*32768
  int t = idx >> 15, r = idx & 32767;
  int b = r >> 10, s = r & 1023;
  const float* base = afull + (size_t)t * 524288 + (size_t)b * 16384;
  float acc = 0.f;
  #pragma unroll
  for (int h = 0; h < 16; h++) acc += base[h * 1024 + s];
  out[idx] = acc * (1.f / 16.f);
}

extern "C" void kernel_launch(void* const* d_in, const int* in_sizes, int n_in,
                              void* d_out, int out_size, void* d_ws, size_t ws_size,
                              hipStream_t stream) {
  const float* comp      = (const float*)d_in[0];
  const float* rule_w1   = (const float*)d_in[2];
  const float* rule_b1   = (const float*)d_in[3];
  const float* rule_w2   = (const float*)d_in[4];
  const float* rule_b2   = (const float*)d_in[5];
  const float* rule_emb  = (const float*)d_in[6];
  const float* attn_in_w = (const float*)d_in[7];
  const float* attn_in_b = (const float*)d_in[8];
  const float* attn_out_w= (const float*)d_in[9];
  const float* attn_out_b= (const float*)d_in[10];
  const float* wih0 = (const float*)d_in[11];
  const float* whh0 = (const float*)d_in[12];
  const float* bih0 = (const float*)d_in[13];
  const float* bhh0 = (const float*)d_in[14];
  const float* wih1 = (const float*)d_in[15];
  const float* whh1 = (const float*)d_in[16];
  const float* bih1 = (const float*)d_in[17];
  const float* bhh1 = (const float*)d_in[18];
  const float* gen_w1 = (const float*)d_in[19];
  const float* gen_b1 = (const float*)d_in[20];
  const float* ln_g   = (const float*)d_in[21];
  const float* ln_b   = (const float*)d_in[22];
  const float* gen_w2 = (const float*)d_in[23];
  const float* gen_b2 = (const float*)d_in[24];
  const float* val_w1 = (const float*)d_in[25];
  const float* val_b1 = (const float*)d_in[26];
  const float* val_w2 = (const float*)d_in[27];
  const float* val_b2 = (const float*)d_in[28];
  const float* ver_w1 = (const float*)d_in[29];
  const float* ver_b1 = (const float*)d_in[30];
  const float* ver_w2 = (const float*)d_in[31];
  const float* ver_b2 = (const float*)d_in[32];

  float* out_f     = (float*)d_out;
  float* out_proof = out_f;                       // (17,32,1024)
  float* out_valid = out_f + 17 * 32768;          // (32,1)
  float* out_probs = out_valid + 32;              // (16,32,32)
  float* out_vals  = out_probs + 16 * 1024;       // (16,32,1)
  float* out_attn  = out_vals + 16 * 32;          // (16,32,1024)

  char* wp = (char*)d_ws;
  auto carve = [&](size_t bytes) -> void* {
    void* p = (void*)wp; wp += (bytes + 255) & ~(size_t)255; return p;
  };
  u16* Kt    = (u16*)carve((size_t)33554432 * 2);   // [b][hd][s]
  u16* Vb    = (u16*)carve((size_t)33554432 * 2);   // [b][s][hd]
  u16* compb = (u16*)carve((size_t)33554432 * 2);   // bf16 comp; afull_all aliases after gemms
  float* afull_all = (float*)compb;                 // 16 * 512 * 1024 fp32 = 32MB (<= 64MB)
  u16* rw1b  = (u16*)carve(2097152);
  u16* wqb   = (u16*)carve(2097152);
  u16* wkb   = (u16*)carve(2097152);
  u16* wvb   = (u16*)carve(2097152);
  u16* aowb  = (u16*)carve(2097152);
  u16* wih0b = (u16*)carve(8388608);
  u16* whh0b = (u16*)carve(8388608);
  u16* wih1b = (u16*)carve(8388608);
  u16* whh1b = (u16*)carve(8388608);
  u16* gw1b  = (u16*)carve(4194304);
  u16* gw2b  = (u16*)carve(4194304);
  u16* vw1b  = (u16*)carve(4194304);
  u16* verw1b= (u16*)carve(2097152);
  float* psb[2]  = { (float*)carve(131072), (float*)carve(131072) };
  float* h0b[2]  = { (float*)carve(131072), (float*)carve(131072) };
  float* c0b[2]  = { (float*)carve(131072), (float*)carve(131072) };
  float* h1b[2]  = { (float*)carve(131072), (float*)carve(131072) };
  float* c1b[2]  = { (float*)carve(131072), (float*)carve(131072) };
  float* h1act = (float*)carve(131072);
  float* sel   = (float*)carve(131072);
  float* qbuf  = (float*)carve(131072);
  float* ctx0  = (float*)carve(131072);
  float* ctxb  = (float*)carve(131072);
  float* zbuf  = (float*)carve(262144);
  float* v1buf = (float*)carve(2228224);            // 17 * 32768 fp32
  float* lnstats = (float*)carve(256);              // rowsum[32] + rowsumsq[32]
  (void)ws_size; (void)in_sizes; (void)n_in; (void)out_size;

  // ---- weight casts (one launch) + comp cast ----
  CastJobs J;
  const float* srcs[13] = { rule_w1, attn_in_w, attn_in_w + 1048576, attn_in_w + 2097152,
                            attn_out_w, wih0, whh0, wih1, whh1, gen_w1, gen_w2, val_w1, ver_w1 };
  u16* dsts[13] = { rw1b, wqb, wkb, wvb, aowb, wih0b, whh0b, wih1b, whh1b, gw1b, gw2b, vw1b, verw1b };
  int sizes[13] = { 1048576, 1048576, 1048576, 1048576, 1048576,
                    4194304, 4194304, 4194304, 4194304, 2097152, 2097152, 2097152, 1048576 };
  int st = 0;
  for (int i = 0; i < 13; i++){ J.s[i] = srcs[i]; J.d[i] = dsts[i]; J.start[i] = st; st += sizes[i] / 1024; }
  J.start[13] = st;
  cast_all_k<<<dim3(st), dim3(256), 0, stream>>>(J);
  cast_k<<<dim3(32768), dim3(256), 0, stream>>>(comp, compb, 33554432);

  gemmkv_k<<<dim3(2048, 1, 2), dim3(256), 0, stream>>>(compb, wkb, wvb,
      attn_in_b + 1024, attn_in_b + 2048, Kt, Vb);

  init_k<<<dim3(128), dim3(256), 0, stream>>>(comp, psb[0], out_proof,
      h0b[0], c0b[0], h1b[0], c1b[0]);

  auto mkseg = [&](const float* X0, const float* Xa, const float* Xb, const float* Xc,
                   int K1, const u16* W1, int ld1, const float* bb1,
                   const float* Y, int K2, const u16* W2, int ld2, const float* bb2,
                   float* out, int N, int act, float scl, float* out2) -> LinSeg {
    LinSeg S = {};
    S.X0 = X0; S.Xa = Xa; S.Xb = Xb; S.Xc = Xc; S.K1 = K1; S.W1 = W1; S.ld1 = ld1; S.b1 = bb1;
    S.Y = Y; S.K2 = K2; S.W2 = W2; S.ld2 = ld2; S.b2 = bb2;
    S.out = out; S.N = N; S.act = act; S.scale = scl; S.out2 = out2;
    return S;
  };
  auto lin1 = [&](LinSeg S){
    linmulti_k<<<dim3(S.N / 32), dim3(512), 0, stream>>>(S, S, S, S.N / 32, 0, nullptr);
  };

  for (int t = 0; t < 16; t++){
    int cur = t & 1, nx = cur ^ 1;
    float* ps = psb[cur];
    float* afull_t = afull_all + (size_t)t * 524288;
    // D1: rule h1 (gelu) + q (scaled) + LSTM0 complete (gate-grouped epilogue)
    LinSeg sRule = mkseg(ps, 0, 0, 0, 1024, rw1b, 1024, rule_b1, 0, 0, 0, 0, 0, h1act, 1024, 1, 0.f, 0);
    LinSeg sQ    = mkseg(ps, 0, 0, 0, 1024, wqb, 1024, attn_in_b, 0, 0, 0, 0, 0, qbuf, 1024, 2, 0.125f, 0);
    LinSeg sL0   = mkseg(ps, 0, 0, 0, 1024, wih0b, 1024, bih0, h0b[cur], 1024, whh0b, 1024, bhh0,
                         0, 4096, 0, 0.f, 0);
    sL0.gate = 1; sL0.cprev = c0b[cur]; sL0.cout = c0b[nx]; sL0.hout = h0b[nx];
    linmulti_k<<<dim3(192), dim3(512), 0, stream>>>(sRule, sQ, sL0, 32, 32, nullptr);
    // D2: attention + rule2 softmax/sel
    attn_r2_k<<<dim3(544), dim3(256), 0, stream>>>(qbuf, Kt, Vb, afull_t, ctx0,
        h1act, rule_w2, rule_b2, rule_emb, out_probs + t * 1024, sel);
    // D3: ctx proj + LSTM1 complete + zero LN stats
    LinSeg sCtx = mkseg(ctx0, 0, 0, 0, 1024, aowb, 1024, attn_out_b, 0, 0, 0, 0, 0, ctxb, 1024, 0, 0.f, 0);
    LinSeg sL1  = mkseg(h0b[nx], 0, 0, 0, 1024, wih1b, 1024, bih1, h1b[cur], 1024, whh1b, 1024, bhh1,
                        0, 4096, 0, 0.f, 0);
    sL1.gate = 1; sL1.cprev = c1b[cur]; sL1.cout = c1b[nx]; sL1.hout = h1b[nx];
    linmulti_k<<<dim3(160), dim3(512), 0, stream>>>(sCtx, sL1, sL1, 32, 128, lnstats);
    // D4: z = (ps+sel+ctx+mem) @ gw1^T + b, epilogue accumulates LN row stats
    LinSeg sG1 = mkseg(ps, sel, ctxb, h1b[nx], 1024, gw1b, 1024, gen_b1, 0, 0, 0, 0, 0,
                       zbuf, 2048, 0, 0.f, 0);
    sG1.stats = lnstats;
    lin1(sG1);
    // D5: nxt = gelu(LN(z)) @ gw2^T + b   (LN+gelu applied on A-load)
    LinSeg sG2 = mkseg(zbuf, 0, 0, 0, 2048, gw2b, 2048, gen_b2, 0, 0, 0, 0, 0,
                       psb[nx], 1024, 0, 0.f, out_proof + (size_t)(t + 1) * 32768);
    sG2.lng = ln_g; sG2.lnb = ln_b; sG2.lnstats = lnstats;
    lin1(sG2);
  }
  // post-loop: batched value heads (16) + verifier (grid.y = 17)
  valver_k<<<dim3(32, 17), dim3(512), 0, stream>>>(vw1b, val_b1, verw1b, ver_b1, out_proof, v1buf);
  dotsig_b_k<<<dim3(17), dim3(256), 0, stream>>>(v1buf, val_w2, val_b2, ver_w2, ver_b2,
      out_vals, out_valid);
  // batched attn head-mean
  attnavg_all_k<<<dim3(2048), dim3(256), 0, stream>>>(afull_all, out_attn);
}